// Round 1
// baseline (1686.680 us; speedup 1.0000x reference)
//
#include <hip/hip_runtime.h>
#include <cmath>

// Problem constants (B,N,DIM,HEADS)=(4,4096,1024,16), SX=SY=2, ratio .9
#define B_  4
#define N_  4096
#define C_  1024
#define H_  16
#define D_  64
#define ND_ 1024   // num dst tokens (one per 2x2 block)
#define NA_ 3072   // num src (a) tokens
// r = min(3072, int(4096*0.9)) = 3072  => unm empty, sort permutation cancels.

// ---------------------------------------------------------------------------
// threefry2x32 (20 rounds), returns BOTH output words.
// ---------------------------------------------------------------------------
__device__ inline void tf2x32(unsigned k0, unsigned k1, unsigned x0, unsigned x1,
                              unsigned& o0, unsigned& o1) {
  const unsigned ks2 = 0x1BD11BDAu ^ k0 ^ k1;
  x0 += k0; x1 += k1;
#define RND_(r) { x0 += x1; x1 = (x1 << (r)) | (x1 >> (32 - (r))); x1 ^= x0; }
  RND_(13) RND_(15) RND_(26) RND_(6)
  x0 += k1;  x1 += ks2 + 1u;
  RND_(17) RND_(29) RND_(16) RND_(24)
  x0 += ks2; x1 += k0 + 2u;
  RND_(13) RND_(15) RND_(26) RND_(6)
  x0 += k0;  x1 += k1 + 3u;
  RND_(17) RND_(29) RND_(16) RND_(24)
  x0 += k1;  x1 += ks2 + 4u;
  RND_(13) RND_(15) RND_(26) RND_(6)
  x0 += ks2; x1 += k0 + 5u;
#undef RND_
  o0 = x0; o1 = x1;
}

// ---------------------------------------------------------------------------
// K1 (VERIFIED r7): jax.random.randint(key(33),(32,32),0,4):
// k2 = split(key)[1] = threefry_out((0,33),(0,1)); element p ->
// threefry(k2,(0,p)), value = (bits1^bits2) & 3.
// ---------------------------------------------------------------------------
__global__ __launch_bounds__(1024) void k_init_indices(int* __restrict__ b_idx,
                                                       int* __restrict__ a_idx) {
  __shared__ unsigned char randk[1024];
  __shared__ int wtot[16], wpre[16];
  const int tid = threadIdx.x;
  {
    unsigned c0, c1;
    tf2x32(0u, 33u, 0u, 1u, c0, c1);                 // k2 = split(key)[1]
    unsigned d0, d1;
    tf2x32(c0, c1, 0u, (unsigned)tid, d0, d1);       // random_bits element p
    randk[tid] = (unsigned char)((d0 ^ d1) & 3u);    // xor-fold, % span
  }
  __syncthreads();
  const int base_t = tid * 4;
  int f[4]; int cnt = 0;
#pragma unroll
  for (int j = 0; j < 4; j++) {
    const int t = base_t + j;
    const int y = t >> 6, xc = t & 63;
    const int bi = (y >> 1) * 32 + (xc >> 1);
    const int k  = (y & 1) * 2 + (xc & 1);
    f[j] = (randk[bi] == (unsigned char)k) ? 1 : 0;
    cnt += f[j];
  }
  const int lane = tid & 63, wave = tid >> 6;
  int incl = cnt;
#pragma unroll
  for (int off = 1; off < 64; off <<= 1) {
    int nb = __shfl_up(incl, off, 64);
    if (lane >= off) incl += nb;
  }
  if (lane == 63) wtot[wave] = incl;
  __syncthreads();
  if (tid == 0) { int s = 0; for (int w = 0; w < 16; w++) { wpre[w] = s; s += wtot[w]; } }
  __syncthreads();
  int P = wpre[wave] + (incl - cnt);   // #dst strictly before base_t
#pragma unroll
  for (int j = 0; j < 4; j++) {
    const int t = base_t + j;
    if (f[j]) { b_idx[P] = t; P++; }
    else      { a_idx[t - P] = t; }
  }
}

// ---------------------------------------------------------------------------
// K2: per-token inverse L2 norm of x, fp64
// ---------------------------------------------------------------------------
__global__ __launch_bounds__(256) void k_row_norms(const float* __restrict__ x,
                                                   double* __restrict__ dinv) {
  const int row = blockIdx.x;                 // B_*N_
  const float* xr = x + (size_t)row * C_;
  const int tid = threadIdx.x;
  float4 v = ((const float4*)xr)[tid];
  double s = (double)v.x * (double)v.x + (double)v.y * (double)v.y +
             (double)v.z * (double)v.z + (double)v.w * (double)v.w;
#pragma unroll
  for (int off = 32; off; off >>= 1) s += __shfl_down(s, off, 64);
  __shared__ double wsum[4];
  if ((tid & 63) == 0) wsum[tid >> 6] = s;
  __syncthreads();
  if (tid == 0) {
    double t = wsum[0] + wsum[1] + wsum[2] + wsum[3];
    dinv[row] = 1.0 / sqrt(t);
  }
}

// top-2 merge tracking both indices
__device__ inline void top2m(float& v1, int& i1, float& v2, int& i2,
                             float ov1, int oi1, float ov2, int oi2) {
  if (ov1 > v1 || (ov1 == v1 && oi1 < i1)) {
    if (v1 > ov2 || (v1 == ov2 && i1 < oi2)) { v2 = v1; i2 = i1; }
    else { v2 = ov2; i2 = oi2; }
    v1 = ov1; i1 = oi1;
  } else if (ov1 > v2 || (ov1 == v2 && oi1 < i2)) {
    v2 = ov1; i2 = oi1;
  }
}

// ---------------------------------------------------------------------------
// K3: fp32 scores 64x64 tile GEMM, top-2 (values+indices) epilogue.
// ---------------------------------------------------------------------------
__global__ __launch_bounds__(256) void k_scores(
    const float* __restrict__ x, const double* __restrict__ dinv,
    const int* __restrict__ a_idx, const int* __restrict__ b_idx,
    float* __restrict__ pv1, int* __restrict__ pi1,
    float* __restrict__ pv2, int* __restrict__ pi2) {
  __shared__ __align__(16) float As[16][68];
  __shared__ __align__(16) float Bs[16][68];
  const int bz = blockIdx.z, cb = blockIdx.x, sb = blockIdx.y;
  const int tid = threadIdx.x;
  const int tx = tid & 15, ty = tid >> 4;
  const int lm = tid >> 2, lk = (tid & 3) * 4;
  const int ga = a_idx[sb * 64 + lm];
  const int gb = b_idx[cb * 64 + lm];
  const float ia = (float)dinv[bz * N_ + ga];
  const float ib = (float)dinv[bz * N_ + gb];
  const float* __restrict__ xa = x + ((size_t)bz * N_ + ga) * C_;
  const float* __restrict__ xb = x + ((size_t)bz * N_ + gb) * C_;
  float acc[4][4] = {};
  for (int k0 = 0; k0 < C_; k0 += 16) {
    const float4 av = *(const float4*)(xa + k0 + lk);
    const float4 bv = *(const float4*)(xb + k0 + lk);
    __syncthreads();
    As[lk + 0][lm] = av.x * ia; As[lk + 1][lm] = av.y * ia;
    As[lk + 2][lm] = av.z * ia; As[lk + 3][lm] = av.w * ia;
    Bs[lk + 0][lm] = bv.x * ib; Bs[lk + 1][lm] = bv.y * ib;
    Bs[lk + 2][lm] = bv.z * ib; Bs[lk + 3][lm] = bv.w * ib;
    __syncthreads();
#pragma unroll
    for (int k = 0; k < 16; k++) {
      const float4 a4 = *(const float4*)&As[k][ty * 4];
      const float4 b4 = *(const float4*)&Bs[k][tx * 4];
      const float ar[4] = {a4.x, a4.y, a4.z, a4.w};
      const float br[4] = {b4.x, b4.y, b4.z, b4.w};
#pragma unroll
      for (int i = 0; i < 4; i++)
#pragma unroll
        for (int j = 0; j < 4; j++) acc[i][j] = fmaf(ar[i], br[j], acc[i][j]);
    }
  }
#pragma unroll
  for (int i = 0; i < 4; i++) {
    float v1 = acc[i][0]; int i1 = cb * 64 + tx * 4;
    float v2 = -INFINITY; int i2 = i1;
#pragma unroll
    for (int j = 1; j < 4; j++) {
      const float v = acc[i][j];
      const int d = cb * 64 + tx * 4 + j;
      if (v > v1) { v2 = v1; i2 = i1; v1 = v; i1 = d; }
      else if (v > v2) { v2 = v; i2 = d; }
    }
#pragma unroll
    for (int off = 8; off; off >>= 1) {
      const float ov1 = __shfl_xor(v1, off, 16);
      const int   oi1 = __shfl_xor(i1, off, 16);
      const float ov2 = __shfl_xor(v2, off, 16);
      const int   oi2 = __shfl_xor(i2, off, 16);
      top2m(v1, i1, v2, i2, ov1, oi1, ov2, oi2);
    }
    if (tx == 0) {
      const int s = sb * 64 + ty * 4 + i;
      const size_t o = ((size_t)bz * NA_ + s) * 16 + cb;
      pv1[o] = v1; pi1[o] = i1; pv2[o] = v2; pi2[o] = i2;
    }
  }
}

// K4: merge 16 per-tile partials -> node_idx + near-tie flag
__global__ __launch_bounds__(256) void k_finalize(
    const float* __restrict__ pv1, const int* __restrict__ pi1,
    const float* __restrict__ pv2, const int* __restrict__ pi2,
    int* __restrict__ node_idx, int* __restrict__ flagr) {
  const int r = blockIdx.x * 256 + threadIdx.x;   // [0, B_*NA_)
  if (r >= B_ * NA_) return;
  size_t o = (size_t)r * 16;
  float v1 = pv1[o]; int i1 = pi1[o]; float v2 = pv2[o]; int i2 = pi2[o];
  for (int cb = 1; cb < 16; cb++)
    top2m(v1, i1, v2, i2, pv1[o + cb], pi1[o + cb], pv2[o + cb], pi2[o + cb]);
  node_idx[r] = i1;
  flagr[r] = (v1 - v2 < 3e-4f) ? 1 : 0;  // fp32 GEMM error ~1e-5 << 3e-4
}

// ---------------------------------------------------------------------------
// K5: candidate-based fp64 recheck for flagged rows.
// Candidates: per-tile top1 always; top2 if within 3e-4 of global v1;
// full 64-dst tile scan if tile v2 within 5e-5 of v1 (covers >=3-way ties).
// ---------------------------------------------------------------------------
__global__ __launch_bounds__(256) void k_recheck(
    const float* __restrict__ x, const double* __restrict__ dinv,
    const int* __restrict__ a_idx, const int* __restrict__ b_idx,
    const float* __restrict__ pv1, const int* __restrict__ pi1,
    const float* __restrict__ pv2, const int* __restrict__ pi2,
    const int* __restrict__ flagr, int* __restrict__ node_idx) {
  const int r = blockIdx.x;                 // bz*NA_ + s
  if (!flagr[r]) return;
  const int bz = r / NA_, s = r % NA_;
  __shared__ double arow[C_];
  __shared__ int cand[1088];
  __shared__ int ncand;
  __shared__ float v1s[16];
  const int tid = threadIdx.x;
  const int ga = a_idx[s];
  const double ia = dinv[bz * N_ + ga];
  const float* xa = x + ((size_t)bz * N_ + ga) * C_;
  for (int c = tid; c < C_; c += 256) arow[c] = (double)xa[c] * ia;
  const size_t o = (size_t)r * 16;
  if (tid < 16) v1s[tid] = pv1[o + tid];
  if (tid == 0) ncand = 0;
  __syncthreads();
  // global fp32 v1
  float v1g = v1s[0];
#pragma unroll
  for (int cb = 1; cb < 16; cb++) v1g = fmaxf(v1g, v1s[cb]);
  // build candidate list (threads 0..15 handle one tile each)
  if (tid < 16) {
    const float tv1 = pv1[o + tid], tv2 = pv2[o + tid];
    if (tv2 >= v1g - 5e-5f) {
      // rare: >=2 near-max in one tile -> scan whole tile
      const int base = atomicAdd(&ncand, 64);
      for (int j = 0; j < 64; j++) cand[base + j] = tid * 64 + j;
    } else {
      if (tv1 >= v1g - 3e-4f) { cand[atomicAdd(&ncand, 1)] = pi1[o + tid]; }
      if (tv2 >= v1g - 3e-4f) { cand[atomicAdd(&ncand, 1)] = pi2[o + tid]; }
    }
  }
  __syncthreads();
  const int nc = ncand;
  const int lane = tid & 63, wave = tid >> 6;
  double bv = -1e300; int bi = 1 << 30;
  for (int ci = wave; ci < nc; ci += 4) {
    const int d = cand[ci];
    const int gb = b_idx[d];
    const double ib = dinv[bz * N_ + gb];
    const float* xb = x + ((size_t)bz * N_ + gb) * C_;
    double sum = 0.0;
    for (int c = lane; c < C_; c += 64) sum += arow[c] * ((double)xb[c] * ib);
#pragma unroll
    for (int off = 32; off; off >>= 1) sum += __shfl_xor(sum, off, 64);
    if (sum > bv || (sum == bv && d < bi)) { bv = sum; bi = d; }
  }
  __shared__ double bvs[4]; __shared__ int bis[4];
  if (lane == 0) { bvs[wave] = bv; bis[wave] = bi; }
  __syncthreads();
  if (tid == 0) {
    for (int w = 1; w < 4; w++)
      if (bvs[w] > bv || (bvs[w] == bv && bis[w] < bi)) { bv = bvs[w]; bi = bis[w]; }
    node_idx[r] = bi;
  }
}

// K6: counts per dst + token->merged-row map
__global__ __launch_bounds__(256) void k_counts_rowmap(
    const int* __restrict__ a_idx, const int* __restrict__ b_idx,
    const int* __restrict__ node_idx, int* __restrict__ cnt,
    int* __restrict__ rowmap) {
  const int i = blockIdx.x * 256 + threadIdx.x;   // [0, B_*N_)
  if (i >= B_ * N_) return;
  const int bz = i >> 12, j = i & 4095;
  if (j < NA_) {
    const int nd = node_idx[bz * NA_ + j];
    atomicAdd(&cnt[bz * ND_ + nd], 1);
    rowmap[bz * N_ + a_idx[j]] = nd;
  } else {
    const int d = j - NA_;
    rowmap[bz * N_ + b_idx[d]] = d;
  }
}

// K7/K8/K9: merge x into xm
__global__ __launch_bounds__(256) void k_merge_init(const float* __restrict__ x,
                                                    const int* __restrict__ b_idx,
                                                    float* __restrict__ xm) {
  const int blk = blockIdx.x;                 // B_*ND_
  const int bz = blk >> 10, d = blk & 1023;
  const float4* src = (const float4*)(x + ((size_t)bz * N_ + b_idx[d]) * C_);
  float4* dst = (float4*)(xm + ((size_t)bz * ND_ + d) * C_);
  dst[threadIdx.x] = src[threadIdx.x];
}

__global__ __launch_bounds__(256) void k_merge_add(const float* __restrict__ x,
                                                   const int* __restrict__ a_idx,
                                                   const int* __restrict__ node_idx,
                                                   float* __restrict__ xm) {
  const int blk = blockIdx.x;                 // B_*NA_ = bz*NA_+i
  const int bz = blk / NA_, i = blk % NA_;
  const int nd = node_idx[blk];
  const float* src = x + ((size_t)bz * N_ + a_idx[i]) * C_;
  float* dst = xm + ((size_t)bz * ND_ + nd) * C_;
  const int c0 = threadIdx.x * 4;
  const float4 v = *(const float4*)(src + c0);
  atomicAdd(&dst[c0 + 0], v.x);
  atomicAdd(&dst[c0 + 1], v.y);
  atomicAdd(&dst[c0 + 2], v.z);
  atomicAdd(&dst[c0 + 3], v.w);
}

__global__ __launch_bounds__(256) void k_merge_scale(float* __restrict__ xm,
                                                     const int* __restrict__ cnt) {
  const int blk = blockIdx.x;                 // B_*ND_
  const float s = 1.0f + (float)cnt[blk];
  float4* p = (float4*)(xm + (size_t)blk * C_);
  float4 v = p[threadIdx.x];
  v.x /= s; v.y /= s; v.z /= s; v.w /= s;
  p[threadIdx.x] = v;
}

// ---------------------------------------------------------------------------
// K10: qkv GEMM, 128x128 tile, 8x8 per thread, BK=8.
// qkvm[b][w][h][t][d] = xm @ W_qkv^T   (M=4096, N=3072, K=1024)
// ---------------------------------------------------------------------------
__global__ __launch_bounds__(256) void k_qkv(const float* __restrict__ xm,
                                             const float* __restrict__ Wqkv,
                                             float* __restrict__ qkvm) {
  __shared__ __align__(16) float As[8][132];
  __shared__ __align__(16) float Bs[8][132];
  const int nb = blockIdx.x;   // 24
  const int mb = blockIdx.y;   // 32
  const int tid = threadIdx.x;
  const int tx = tid & 15, ty = tid >> 4;
  const int lr = tid >> 1;            // 0..127
  const int lkc = (tid & 1) * 4;      // 0 or 4
  const float* __restrict__ ar = xm + (size_t)(mb * 128 + lr) * C_ + lkc;
  const float* __restrict__ br = Wqkv + (size_t)(nb * 128 + lr) * C_ + lkc;
  float acc[8][8] = {};
  for (int k0 = 0; k0 < C_; k0 += 8) {
    const float4 av = *(const float4*)(ar + k0);
    const float4 bv = *(const float4*)(br + k0);
    __syncthreads();
    As[lkc + 0][lr] = av.x; As[lkc + 1][lr] = av.y;
    As[lkc + 2][lr] = av.z; As[lkc + 3][lr] = av.w;
    Bs[lkc + 0][lr] = bv.x; Bs[lkc + 1][lr] = bv.y;
    Bs[lkc + 2][lr] = bv.z; Bs[lkc + 3][lr] = bv.w;
    __syncthreads();
#pragma unroll
    for (int k = 0; k < 8; k++) {
      float a_[8], b_[8];
      *(float4*)&a_[0] = *(const float4*)&As[k][ty * 8];
      *(float4*)&a_[4] = *(const float4*)&As[k][ty * 8 + 4];
      *(float4*)&b_[0] = *(const float4*)&Bs[k][tx * 8];
      *(float4*)&b_[4] = *(const float4*)&Bs[k][tx * 8 + 4];
#pragma unroll
      for (int i = 0; i < 8; i++)
#pragma unroll
        for (int j = 0; j < 8; j++) acc[i][j] = fmaf(a_[i], b_[j], acc[i][j]);
    }
  }
  const int n0 = nb * 128 + tx * 8;
  const int w = n0 >> 10, h = (n0 >> 6) & 15, dc = n0 & 63;   // 8 cols within 1 head
#pragma unroll
  for (int i = 0; i < 8; i++) {
    const int m = mb * 128 + ty * 8 + i;
    const int bb = m >> 10, t = m & 1023;
    float* dst = qkvm + (((size_t)(bb * 3 + w) * 16 + h) * 1024 + t) * 64 + dc;
    *(float4*)dst       = make_float4(acc[i][0], acc[i][1], acc[i][2], acc[i][3]);
    *(float4*)(dst + 4) = make_float4(acc[i][4], acc[i][5], acc[i][6], acc[i][7]);
  }
}

// ---------------------------------------------------------------------------
// K11: flash attention.
//  - kps buffer is ksT during QK^T phase, swizzled psT during PV phase
//    (alias saves 16.6 KB -> 3 blocks/CU instead of 2).
//  - psT stored with XOR swizzle col' = col ^ ((row>>2)&3): scalar epilogue
//    writes go from 8-way bank conflict to conflict-free; the swizzle only
//    permutes within a float4 group, undone by compile-time component pick.
//  - mi/li live in registers (replicated across the 16-lane row group).
//  - next K/V tile prefetched into registers to overlap global latency.
// All arithmetic order identical to previous version -> bitwise same output.
// ---------------------------------------------------------------------------
__global__ __launch_bounds__(256) void k_attn(const float* __restrict__ qkvm,
                                              float* __restrict__ om) {
  __shared__ float qsT[64][65];   // [d][qtok]
  __shared__ float kps[64][65];   // phase1: ksT [d][ktok]; phase2: psT [ktok][qrow^swz]
  __shared__ float vs[64][65];    // [ktok][d]
  const int qb = blockIdx.x, h = blockIdx.y, bz = blockIdx.z;
  const int tid = threadIdx.x;
  const int tx = tid & 15, ty = tid >> 4;
  const float* __restrict__ qp = qkvm + (((size_t)(bz * 3 + 0) * 16 + h) * 1024) * 64;
  const float* __restrict__ kp = qkvm + (((size_t)(bz * 3 + 1) * 16 + h) * 1024) * 64;
  const float* __restrict__ vp = qkvm + (((size_t)(bz * 3 + 2) * 16 + h) * 1024) * 64;
  const int lr = tid >> 2, lc = (tid & 3) * 16;
  {
    const float4* src = (const float4*)(qp + (size_t)(qb * 64 + lr) * 64 + lc);
#pragma unroll
    for (int j = 0; j < 4; j++) {
      const float4 v4 = src[j];
      qsT[lc + j * 4 + 0][lr] = v4.x * 0.125f;
      qsT[lc + j * 4 + 1][lr] = v4.y * 0.125f;
      qsT[lc + j * 4 + 2][lr] = v4.z * 0.125f;
      qsT[lc + j * 4 + 3][lr] = v4.w * 0.125f;
    }
  }
  // prefetch K/V tile 0 into registers
  float4 kreg[4], vreg[4];
  {
    const float4* ksrc = (const float4*)(kp + (size_t)lr * 64 + lc);
    const float4* vsrc = (const float4*)(vp + (size_t)lr * 64 + lc);
#pragma unroll
    for (int j = 0; j < 4; j++) { kreg[j] = ksrc[j]; vreg[j] = vsrc[j]; }
  }
  float m_r[4], l_r[4];
#pragma unroll
  for (int i = 0; i < 4; i++) { m_r[i] = -INFINITY; l_r[i] = 0.0f; }
  float o[4][4] = {};
  float alpha[4];
  for (int kt = 0; kt < 16; kt++) {
    __syncthreads();          // prev tile's PV reads of kps/vs complete
    // stage registers -> LDS
#pragma unroll
    for (int j = 0; j < 4; j++) {
      const float4 kv = kreg[j], vv = vreg[j];
      kps[lc + j * 4 + 0][lr] = kv.x; kps[lc + j * 4 + 1][lr] = kv.y;
      kps[lc + j * 4 + 2][lr] = kv.z; kps[lc + j * 4 + 3][lr] = kv.w;
      vs[lr][lc + j * 4 + 0] = vv.x; vs[lr][lc + j * 4 + 1] = vv.y;
      vs[lr][lc + j * 4 + 2] = vv.z; vs[lr][lc + j * 4 + 3] = vv.w;
    }
    // issue next tile's global loads (overlap with compute below)
    if (kt < 15) {
      const float4* ksrc = (const float4*)(kp + (size_t)((kt + 1) * 64 + lr) * 64 + lc);
      const float4* vsrc = (const float4*)(vp + (size_t)((kt + 1) * 64 + lr) * 64 + lc);
#pragma unroll
      for (int j = 0; j < 4; j++) { kreg[j] = ksrc[j]; vreg[j] = vsrc[j]; }
    }
    __syncthreads();          // staging visible
    // QK^T: reads qsT + kps(=ksT)
    float sacc[4][4] = {};
#pragma unroll 4
    for (int c = 0; c < 64; c++) {
      const float4 a4 = *(const float4*)&qsT[c][ty * 4];
      const float4 b4 = *(const float4*)&kps[c][tx * 4];
      const float a_[4] = {a4.x, a4.y, a4.z, a4.w};
      const float b_[4] = {b4.x, b4.y, b4.z, b4.w};
#pragma unroll
      for (int i = 0; i < 4; i++)
#pragma unroll
        for (int j = 0; j < 4; j++) sacc[i][j] = fmaf(a_[i], b_[j], sacc[i][j]);
    }
    // online softmax, m/l in registers (replicated across the 16-lane group)
#pragma unroll
    for (int i = 0; i < 4; i++) {
      float tmax = fmaxf(fmaxf(sacc[i][0], sacc[i][1]), fmaxf(sacc[i][2], sacc[i][3]));
#pragma unroll
      for (int off = 8; off; off >>= 1) tmax = fmaxf(tmax, __shfl_xor(tmax, off, 16));
      const float mold = m_r[i];
      const float mn = fmaxf(mold, tmax);
      alpha[i] = expf(mold - mn);
      float s_ = 0.0f;
#pragma unroll
      for (int j = 0; j < 4; j++) { sacc[i][j] = expf(sacc[i][j] - mn); s_ += sacc[i][j]; }
#pragma unroll
      for (int off = 8; off; off >>= 1) s_ += __shfl_xor(s_, off, 16);
      m_r[i] = mn;
      l_r[i] = l_r[i] * alpha[i] + s_;
    }
    __syncthreads();          // all QK reads of kps done; safe to overwrite as psT
    // write P^T swizzled: row r=tx*4+j, col = ty*4 + (i ^ (tx&3))
    {
      const int sw = tx & 3;
#pragma unroll
      for (int i = 0; i < 4; i++) {
        const int cc = ty * 4 + (i ^ sw);
#pragma unroll
        for (int j = 0; j < 4; j++) kps[tx * 4 + j][cc] = sacc[i][j];
      }
    }
    __syncthreads();          // psT visible
    // rescale o
#pragma unroll
    for (int i = 0; i < 4; i++)
#pragma unroll
      for (int j = 0; j < 4; j++) o[i][j] *= alpha[i];
    // PV: reads kps(=psT, swizzled) + vs
    for (int g = 0; g < 4; g++) {
#pragma unroll
      for (int u = 0; u < 16; u++) {
        const int d2 = g * 16 + u;
        const int s2 = (u >> 2) & 3;          // == (d2>>2)&3, compile-time
        const float4 p4 = *(const float4*)&kps[d2][ty * 4];
        const float4 v4 = *(const float4*)&vs[d2][tx * 4];
        const float pp[4] = {p4.x, p4.y, p4.z, p4.w};
        const float pr[4] = {pp[0 ^ s2], pp[1 ^ s2], pp[2 ^ s2], pp[3 ^ s2]};
        const float vr[4] = {v4.x, v4.y, v4.z, v4.w};
#pragma unroll
        for (int i = 0; i < 4; i++)
#pragma unroll
          for (int j = 0; j < 4; j++) o[i][j] = fmaf(pr[i], vr[j], o[i][j]);
      }
    }
  }
#pragma unroll
  for (int i = 0; i < 4; i++) {
    const float inv = 1.0f / l_r[i];
    const int t = qb * 64 + ty * 4 + i;
    const float4 st = make_float4(o[i][0] * inv, o[i][1] * inv, o[i][2] * inv, o[i][3] * inv);
    *(float4*)(om + ((size_t)bz * ND_ + t) * C_ + h * 64 + tx * 4) = st;
  }
}

// ---------------------------------------------------------------------------
// K12: proj GEMM, 128x128 tile, 8x8 per thread, BK=8. ym = om@Wp^T + bp
// ---------------------------------------------------------------------------
__global__ __launch_bounds__(256) void k_proj(const float* __restrict__ om,
                                              const float* __restrict__ Wp,
                                              const float* __restrict__ bp,
                                              float* __restrict__ ym) {
  __shared__ __align__(16) float As[8][132];
  __shared__ __align__(16) float Bs[8][132];
  const int nb = blockIdx.x;   // 8
  const int mb = blockIdx.y;   // 32
  const int tid = threadIdx.x;
  const int tx = tid & 15, ty = tid >> 4;
  const int lr = tid >> 1;
  const int lkc = (tid & 1) * 4;
  const float* __restrict__ ar = om + (size_t)(mb * 128 + lr) * C_ + lkc;
  const float* __restrict__ br = Wp + (size_t)(nb * 128 + lr) * C_ + lkc;
  float acc[8][8] = {};
  for (int k0 = 0; k0 < C_; k0 += 8) {
    const float4 av = *(const float4*)(ar + k0);
    const float4 bv = *(const float4*)(br + k0);
    __syncthreads();
    As[lkc + 0][lr] = av.x; As[lkc + 1][lr] = av.y;
    As[lkc + 2][lr] = av.z; As[lkc + 3][lr] = av.w;
    Bs[lkc + 0][lr] = bv.x; Bs[lkc + 1][lr] = bv.y;
    Bs[lkc + 2][lr] = bv.z; Bs[lkc + 3][lr] = bv.w;
    __syncthreads();
#pragma unroll
    for (int k = 0; k < 8; k++) {
      float a_[8], b_[8];
      *(float4*)&a_[0] = *(const float4*)&As[k][ty * 8];
      *(float4*)&a_[4] = *(const float4*)&As[k][ty * 8 + 4];
      *(float4*)&b_[0] = *(const float4*)&Bs[k][tx * 8];
      *(float4*)&b_[4] = *(const float4*)&Bs[k][tx * 8 + 4];
#pragma unroll
      for (int i = 0; i < 8; i++)
#pragma unroll
        for (int j = 0; j < 8; j++) acc[i][j] = fmaf(a_[i], b_[j], acc[i][j]);
    }
  }
  const int n0 = nb * 128 + tx * 8;
  const float4 b0 = *(const float4*)(bp + n0);
  const float4 b1 = *(const float4*)(bp + n0 + 4);
#pragma unroll
  for (int i = 0; i < 8; i++) {
    const int m = mb * 128 + ty * 8 + i;
    float* dst = ym + (size_t)m * C_ + n0;
    *(float4*)dst       = make_float4(acc[i][0] + b0.x, acc[i][1] + b0.y,
                                      acc[i][2] + b0.z, acc[i][3] + b0.w);
    *(float4*)(dst + 4) = make_float4(acc[i][4] + b1.x, acc[i][5] + b1.y,
                                      acc[i][6] + b1.z, acc[i][7] + b1.w);
  }
}

// K13: scatter merged rows back to all 4096 tokens
__global__ __launch_bounds__(256) void k_unmerge(const float* __restrict__ ym,
                                                 const int* __restrict__ rowmap,
                                                 float* __restrict__ out) {
  const int blk = blockIdx.x;                 // B_*N_
  const int bz = blk >> 12;
  const int r = rowmap[blk];
  const float4* src = (const float4*)(ym + ((size_t)bz * ND_ + r) * C_);
  float4* dst = (float4*)(out + (size_t)blk * C_);
  dst[threadIdx.x] = src[threadIdx.x];
}

// ---------------------------------------------------------------------------
extern "C" void kernel_launch(void* const* d_in, const int* in_sizes, int n_in,
                              void* d_out, int out_size, void* d_ws, size_t ws_size,
                              hipStream_t stream) {
  const float* x    = (const float*)d_in[0];
  const float* Wqkv = (const float*)d_in[1];
  const float* Wp   = (const float*)d_in[2];
  const float* bp   = (const float*)d_in[3];
  char* ws = (char*)d_ws;
  double* dinv    = (double*)(ws + 0);          //  131072 B
  int*   b_idx    = (int*)(ws + 131072);        //    4096 B
  int*   a_idx    = (int*)(ws + 135168);        //   12288 B
  int*   node_idx = (int*)(ws + 147456);        //   49152 B
  int*   cnt      = (int*)(ws + 196608);        //   16384 B
  int*   rowmap   = (int*)(ws + 212992);        //   65536 B
  int*   flagr    = (int*)(ws + 278528);        //   49152 B
  float* pv1      = (float*)(ws + 327680);      //  786432 B
  int*   pi1      = (int*)(ws + 1114112);       //  786432 B
  float* pv2      = (float*)(ws + 1900544);     //  786432 B
  int*   pi2      = (int*)(ws + 2686976);       //  786432 B
  float* xm       = (float*)(ws + 3473408);     // 16.78 MB
  float* qkvm     = (float*)(ws + 20250624);    // 50.33 MB
  float* om       = (float*)(ws + 70582272);    // 16.78 MB
  float* ym       = xm;                         // reuse (xm consumed by k_qkv)
  float* out      = (float*)d_out;

  hipMemsetAsync(cnt, 0, B_ * ND_ * sizeof(int), stream);
  k_init_indices<<<1, 1024, 0, stream>>>(b_idx, a_idx);
  k_row_norms<<<B_ * N_, 256, 0, stream>>>(x, dinv);
  k_scores<<<dim3(16, 48, B_), 256, 0, stream>>>(x, dinv, a_idx, b_idx, pv1, pi1, pv2, pi2);
  k_finalize<<<(B_ * NA_) / 256, 256, 0, stream>>>(pv1, pi1, pv2, pi2, node_idx, flagr);
  k_recheck<<<B_ * NA_, 256, 0, stream>>>(x, dinv, a_idx, b_idx, pv1, pi1, pv2, pi2, flagr, node_idx);
  k_counts_rowmap<<<(B_ * N_) / 256, 256, 0, stream>>>(a_idx, b_idx, node_idx, cnt, rowmap);
  k_merge_init<<<B_ * ND_, 256, 0, stream>>>(x, b_idx, xm);
  k_merge_add<<<B_ * NA_, 256, 0, stream>>>(x, a_idx, node_idx, xm);
  k_merge_scale<<<B_ * ND_, 256, 0, stream>>>(xm, cnt);
  k_qkv<<<dim3(24, 32), 256, 0, stream>>>(xm, Wqkv, qkvm);
  k_attn<<<dim3(16, 16, B_), 256, 0, stream>>>(qkvm, om);
  k_proj<<<dim3(8, 32), 256, 0, stream>>>(om, Wp, bp, ym);
  k_unmerge<<<B_ * N_, 256, 0, stream>>>(ym, rowmap, out);
}

// Round 2
// 1546.022 us; speedup vs baseline: 1.0910x; 1.0910x over previous
//
#include <hip/hip_runtime.h>
#include <cmath>

// Problem constants (B,N,DIM,HEADS)=(4,4096,1024,16), SX=SY=2, ratio .9
#define B_  4
#define N_  4096
#define C_  1024
#define H_  16
#define D_  64
#define ND_ 1024   // num dst tokens (one per 2x2 block)
#define NA_ 3072   // num src (a) tokens
// r = min(3072, int(4096*0.9)) = 3072  => unm empty, sort permutation cancels.

typedef __attribute__((ext_vector_type(8))) short short8v;
typedef __attribute__((ext_vector_type(4))) float f32x4;

// ---------------------------------------------------------------------------
// threefry2x32 (20 rounds), returns BOTH output words.
// ---------------------------------------------------------------------------
__device__ inline void tf2x32(unsigned k0, unsigned k1, unsigned x0, unsigned x1,
                              unsigned& o0, unsigned& o1) {
  const unsigned ks2 = 0x1BD11BDAu ^ k0 ^ k1;
  x0 += k0; x1 += k1;
#define RND_(r) { x0 += x1; x1 = (x1 << (r)) | (x1 >> (32 - (r))); x1 ^= x0; }
  RND_(13) RND_(15) RND_(26) RND_(6)
  x0 += k1;  x1 += ks2 + 1u;
  RND_(17) RND_(29) RND_(16) RND_(24)
  x0 += ks2; x1 += k0 + 2u;
  RND_(13) RND_(15) RND_(26) RND_(6)
  x0 += k0;  x1 += k1 + 3u;
  RND_(17) RND_(29) RND_(16) RND_(24)
  x0 += k1;  x1 += ks2 + 4u;
  RND_(13) RND_(15) RND_(26) RND_(6)
  x0 += ks2; x1 += k0 + 5u;
#undef RND_
  o0 = x0; o1 = x1;
}

// ---------------------------------------------------------------------------
// K1 (VERIFIED r7): jax.random.randint(key(33),(32,32),0,4)
// ---------------------------------------------------------------------------
__global__ __launch_bounds__(1024) void k_init_indices(int* __restrict__ b_idx,
                                                       int* __restrict__ a_idx) {
  __shared__ unsigned char randk[1024];
  __shared__ int wtot[16], wpre[16];
  const int tid = threadIdx.x;
  {
    unsigned c0, c1;
    tf2x32(0u, 33u, 0u, 1u, c0, c1);                 // k2 = split(key)[1]
    unsigned d0, d1;
    tf2x32(c0, c1, 0u, (unsigned)tid, d0, d1);       // random_bits element p
    randk[tid] = (unsigned char)((d0 ^ d1) & 3u);    // xor-fold, % span
  }
  __syncthreads();
  const int base_t = tid * 4;
  int f[4]; int cnt = 0;
#pragma unroll
  for (int j = 0; j < 4; j++) {
    const int t = base_t + j;
    const int y = t >> 6, xc = t & 63;
    const int bi = (y >> 1) * 32 + (xc >> 1);
    const int k  = (y & 1) * 2 + (xc & 1);
    f[j] = (randk[bi] == (unsigned char)k) ? 1 : 0;
    cnt += f[j];
  }
  const int lane = tid & 63, wave = tid >> 6;
  int incl = cnt;
#pragma unroll
  for (int off = 1; off < 64; off <<= 1) {
    int nb = __shfl_up(incl, off, 64);
    if (lane >= off) incl += nb;
  }
  if (lane == 63) wtot[wave] = incl;
  __syncthreads();
  if (tid == 0) { int s = 0; for (int w = 0; w < 16; w++) { wpre[w] = s; s += wtot[w]; } }
  __syncthreads();
  int P = wpre[wave] + (incl - cnt);   // #dst strictly before base_t
#pragma unroll
  for (int j = 0; j < 4; j++) {
    const int t = base_t + j;
    if (f[j]) { b_idx[P] = t; P++; }
    else      { a_idx[t - P] = t; }
  }
}

// ---------------------------------------------------------------------------
// K2: per-token inverse L2 norm of x, fp64
// ---------------------------------------------------------------------------
__global__ __launch_bounds__(256) void k_row_norms(const float* __restrict__ x,
                                                   double* __restrict__ dinv) {
  const int row = blockIdx.x;                 // B_*N_
  const float* xr = x + (size_t)row * C_;
  const int tid = threadIdx.x;
  float4 v = ((const float4*)xr)[tid];
  double s = (double)v.x * (double)v.x + (double)v.y * (double)v.y +
             (double)v.z * (double)v.z + (double)v.w * (double)v.w;
#pragma unroll
  for (int off = 32; off; off >>= 1) s += __shfl_down(s, off, 64);
  __shared__ double wsum[4];
  if ((tid & 63) == 0) wsum[tid >> 6] = s;
  __syncthreads();
  if (tid == 0) {
    double t = wsum[0] + wsum[1] + wsum[2] + wsum[3];
    dinv[row] = 1.0 / sqrt(t);
  }
}

// ---------------------------------------------------------------------------
// K2b: normalized rows split into bf16 hi + bf16 lo (RTNE), for MFMA scores.
// xh/xl live in workspace that is later overwritten by qkvm (stream-ordered).
// ---------------------------------------------------------------------------
__device__ inline unsigned short f2bf_rtne(float f) {
  const unsigned u = __float_as_uint(f);
  return (unsigned short)((u + 0x7FFFu + ((u >> 16) & 1u)) >> 16);
}

__global__ __launch_bounds__(256) void k_prep(const float* __restrict__ x,
                                              const double* __restrict__ dinv,
                                              unsigned short* __restrict__ xh,
                                              unsigned short* __restrict__ xl) {
  const int row = blockIdx.x;                 // B_*N_
  const float ia = (float)dinv[row];
  const float4 v = ((const float4*)(x + (size_t)row * C_))[threadIdx.x];
  float f[4] = {v.x * ia, v.y * ia, v.z * ia, v.w * ia};
  unsigned h[4], l[4];
#pragma unroll
  for (int j = 0; j < 4; j++) {
    h[j] = f2bf_rtne(f[j]);
    const float fh = __uint_as_float(h[j] << 16);
    l[j] = f2bf_rtne(f[j] - fh);
  }
  const size_t o = (size_t)row * C_ + threadIdx.x * 4;
  uint2 ph, pl;
  ph.x = h[0] | (h[1] << 16); ph.y = h[2] | (h[3] << 16);
  pl.x = l[0] | (l[1] << 16); pl.y = l[2] | (l[3] << 16);
  *(uint2*)&xh[o] = ph;
  *(uint2*)&xl[o] = pl;
}

// top-2 merge tracking both indices
__device__ inline void top2m(float& v1, int& i1, float& v2, int& i2,
                             float ov1, int oi1, float ov2, int oi2) {
  if (ov1 > v1 || (ov1 == v1 && oi1 < i1)) {
    if (v1 > ov2 || (v1 == ov2 && i1 < oi2)) { v2 = v1; i2 = i1; }
    else { v2 = ov2; i2 = oi2; }
    v1 = ov1; i1 = oi1;
  } else if (ov1 > v2 || (ov1 == v2 && oi1 < i2)) {
    v2 = ov1; i2 = oi1;
  }
}

// ---------------------------------------------------------------------------
// K3: scores via bf16x3 MFMA (a_hi*b_hi + a_hi*b_lo + a_lo*b_hi), 64x64 tile.
// Values only feed argmax; fp64 recheck (K5) guards decisions. Max abs error
// of bf16x3 vs fp32-exact on unit rows: <= ~4e-5 (Cauchy-Schwarz), << the
// 2.5e-4 tile-scan / 1e-3 flag thresholds below.
// 4 waves: wave w -> 32x32 quadrant (wr=w>>1, wc=w&1), 2x2 of 16x16x32 MFMA.
// ---------------------------------------------------------------------------
__global__ __launch_bounds__(256) void k_scores_mfma(
    const unsigned short* __restrict__ xh, const unsigned short* __restrict__ xl,
    const int* __restrict__ a_idx, const int* __restrict__ b_idx,
    float* __restrict__ pv1, int* __restrict__ pi1,
    float* __restrict__ pv2, int* __restrict__ pi2) {
  __shared__ unsigned short Ah[64][40], Al[64][40], Bh[64][40], Bl[64][40];
  __shared__ float mv1[64][2], mv2[64][2];
  __shared__ int   mi1[64][2], mi2[64][2];
  const int bz = blockIdx.z, cb = blockIdx.x, sb = blockIdx.y;
  const int tid = threadIdx.x;
  const int srow = tid >> 2, sq = tid & 3;       // staging row / 16B chunk
  const int ga = a_idx[sb * 64 + srow];
  const int gb = b_idx[cb * 64 + srow];
  const size_t abase = ((size_t)bz * N_ + ga) * C_;
  const size_t bbase = ((size_t)bz * N_ + gb) * C_;
  const int wv = tid >> 6, lane = tid & 63;
  const int wr = wv >> 1, wc = wv & 1;
  const int fr = lane & 15, fg = lane >> 4;      // frag row-in-16 / k-group
  f32x4 acc[2][2] = {};
  for (int k0 = 0; k0 < C_; k0 += 32) {
    __syncthreads();
    *(uint4*)&Ah[srow][sq * 8] = *(const uint4*)(xh + abase + k0 + sq * 8);
    *(uint4*)&Al[srow][sq * 8] = *(const uint4*)(xl + abase + k0 + sq * 8);
    *(uint4*)&Bh[srow][sq * 8] = *(const uint4*)(xh + bbase + k0 + sq * 8);
    *(uint4*)&Bl[srow][sq * 8] = *(const uint4*)(xl + bbase + k0 + sq * 8);
    __syncthreads();
    short8v ah[2], al[2], bh[2], bl[2];
#pragma unroll
    for (int i = 0; i < 2; i++) {
      const int ra = wr * 32 + i * 16 + fr;
      const int rb = wc * 32 + i * 16 + fr;
      ah[i] = *(const short8v*)&Ah[ra][fg * 8];
      al[i] = *(const short8v*)&Al[ra][fg * 8];
      bh[i] = *(const short8v*)&Bh[rb][fg * 8];
      bl[i] = *(const short8v*)&Bl[rb][fg * 8];
    }
#pragma unroll
    for (int i = 0; i < 2; i++)
#pragma unroll
      for (int j = 0; j < 2; j++) {
        acc[i][j] = __builtin_amdgcn_mfma_f32_16x16x32_bf16(al[i], bh[j], acc[i][j], 0, 0, 0);
        acc[i][j] = __builtin_amdgcn_mfma_f32_16x16x32_bf16(ah[i], bl[j], acc[i][j], 0, 0, 0);
        acc[i][j] = __builtin_amdgcn_mfma_f32_16x16x32_bf16(ah[i], bh[j], acc[i][j], 0, 0, 0);
      }
  }
  // top-2 epilogue. D layout: col = lane&15, row = (lane>>4)*4 + reg (m89).
#pragma unroll
  for (int i = 0; i < 2; i++) {
#pragma unroll
    for (int r = 0; r < 4; r++) {
      const float va = acc[i][0][r]; const int ca = cb * 64 + wc * 32 + fr;
      const float vb = acc[i][1][r]; const int cbg = ca + 16;
      float v1, v2; int i1, i2;
      if (vb > va) { v1 = vb; i1 = cbg; v2 = va; i2 = ca; }
      else         { v1 = va; i1 = ca;  v2 = vb; i2 = cbg; }
#pragma unroll
      for (int off = 8; off; off >>= 1) {
        const float ov1 = __shfl_xor(v1, off, 16);
        const int   oi1 = __shfl_xor(i1, off, 16);
        const float ov2 = __shfl_xor(v2, off, 16);
        const int   oi2 = __shfl_xor(i2, off, 16);
        top2m(v1, i1, v2, i2, ov1, oi1, ov2, oi2);
      }
      if (fr == 0) {
        const int rl = wr * 32 + i * 16 + fg * 4 + r;
        mv1[rl][wc] = v1; mi1[rl][wc] = i1; mv2[rl][wc] = v2; mi2[rl][wc] = i2;
      }
    }
  }
  __syncthreads();
  if (tid < 64) {
    float v1 = mv1[tid][0], v2 = mv2[tid][0];
    int   i1 = mi1[tid][0], i2 = mi2[tid][0];
    top2m(v1, i1, v2, i2, mv1[tid][1], mi1[tid][1], mv2[tid][1], mi2[tid][1]);
    const int s = sb * 64 + tid;
    const size_t o = ((size_t)bz * NA_ + s) * 16 + cb;
    pv1[o] = v1; pi1[o] = i1; pv2[o] = v2; pi2[o] = i2;
  }
}

// K4: merge 16 per-tile partials -> node_idx + near-tie flag
// Threshold widened to 1e-3 for bf16x3 scores (error <= ~4e-5).
__global__ __launch_bounds__(256) void k_finalize(
    const float* __restrict__ pv1, const int* __restrict__ pi1,
    const float* __restrict__ pv2, const int* __restrict__ pi2,
    int* __restrict__ node_idx, int* __restrict__ flagr) {
  const int r = blockIdx.x * 256 + threadIdx.x;   // [0, B_*NA_)
  if (r >= B_ * NA_) return;
  size_t o = (size_t)r * 16;
  float v1 = pv1[o]; int i1 = pi1[o]; float v2 = pv2[o]; int i2 = pi2[o];
  for (int cb = 1; cb < 16; cb++)
    top2m(v1, i1, v2, i2, pv1[o + cb], pi1[o + cb], pv2[o + cb], pi2[o + cb]);
  node_idx[r] = i1;
  flagr[r] = (v1 - v2 < 1e-3f) ? 1 : 0;  // unflagged => true gap > 9e-4 => exact
}

// ---------------------------------------------------------------------------
// K5: candidate-based fp64 recheck for flagged rows.
// Candidates: per-tile top1/top2 if within 1e-3 of global v1; full 64-dst
// tile scan if tile v2 within 2.5e-4 of v1 (covers >=3-way ties; 2.5e-4 >= 2*eps).
// ---------------------------------------------------------------------------
__global__ __launch_bounds__(256) void k_recheck(
    const float* __restrict__ x, const double* __restrict__ dinv,
    const int* __restrict__ a_idx, const int* __restrict__ b_idx,
    const float* __restrict__ pv1, const int* __restrict__ pi1,
    const float* __restrict__ pv2, const int* __restrict__ pi2,
    const int* __restrict__ flagr, int* __restrict__ node_idx) {
  const int r = blockIdx.x;                 // bz*NA_ + s
  if (!flagr[r]) return;
  const int bz = r / NA_, s = r % NA_;
  __shared__ double arow[C_];
  __shared__ int cand[1088];
  __shared__ int ncand;
  __shared__ float v1s[16];
  const int tid = threadIdx.x;
  const int ga = a_idx[s];
  const double ia = dinv[bz * N_ + ga];
  const float* xa = x + ((size_t)bz * N_ + ga) * C_;
  for (int c = tid; c < C_; c += 256) arow[c] = (double)xa[c] * ia;
  const size_t o = (size_t)r * 16;
  if (tid < 16) v1s[tid] = pv1[o + tid];
  if (tid == 0) ncand = 0;
  __syncthreads();
  // global bf16x3 v1
  float v1g = v1s[0];
#pragma unroll
  for (int cb = 1; cb < 16; cb++) v1g = fmaxf(v1g, v1s[cb]);
  // build candidate list (threads 0..15 handle one tile each)
  if (tid < 16) {
    const float tv1 = pv1[o + tid], tv2 = pv2[o + tid];
    if (tv2 >= v1g - 2.5e-4f) {
      // >=2 near-max in one tile -> scan whole tile
      const int base = atomicAdd(&ncand, 64);
      for (int j = 0; j < 64; j++) cand[base + j] = tid * 64 + j;
    } else {
      if (tv1 >= v1g - 1e-3f) { cand[atomicAdd(&ncand, 1)] = pi1[o + tid]; }
      if (tv2 >= v1g - 1e-3f) { cand[atomicAdd(&ncand, 1)] = pi2[o + tid]; }
    }
  }
  __syncthreads();
  const int nc = ncand;
  const int lane = tid & 63, wave = tid >> 6;
  double bv = -1e300; int bi = 1 << 30;
  for (int ci = wave; ci < nc; ci += 4) {
    const int d = cand[ci];
    const int gb = b_idx[d];
    const double ib = dinv[bz * N_ + gb];
    const float* xb = x + ((size_t)bz * N_ + gb) * C_;
    double sum = 0.0;
    for (int c = lane; c < C_; c += 64) sum += arow[c] * ((double)xb[c] * ib);
#pragma unroll
    for (int off = 32; off; off >>= 1) sum += __shfl_xor(sum, off, 64);
    if (sum > bv || (sum == bv && d < bi)) { bv = sum; bi = d; }
  }
  __shared__ double bvs[4]; __shared__ int bis[4];
  if (lane == 0) { bvs[wave] = bv; bis[wave] = bi; }
  __syncthreads();
  if (tid == 0) {
    for (int w = 1; w < 4; w++)
      if (bvs[w] > bv || (bvs[w] == bv && bis[w] < bi)) { bv = bvs[w]; bi = bis[w]; }
    node_idx[r] = bi;
  }
}

// K6: counts per dst + token->merged-row map
__global__ __launch_bounds__(256) void k_counts_rowmap(
    const int* __restrict__ a_idx, const int* __restrict__ b_idx,
    const int* __restrict__ node_idx, int* __restrict__ cnt,
    int* __restrict__ rowmap) {
  const int i = blockIdx.x * 256 + threadIdx.x;   // [0, B_*N_)
  if (i >= B_ * N_) return;
  const int bz = i >> 12, j = i & 4095;
  if (j < NA_) {
    const int nd = node_idx[bz * NA_ + j];
    atomicAdd(&cnt[bz * ND_ + nd], 1);
    rowmap[bz * N_ + a_idx[j]] = nd;
  } else {
    const int d = j - NA_;
    rowmap[bz * N_ + b_idx[d]] = d;
  }
}

// K7/K8/K9: merge x into xm
__global__ __launch_bounds__(256) void k_merge_init(const float* __restrict__ x,
                                                    const int* __restrict__ b_idx,
                                                    float* __restrict__ xm) {
  const int blk = blockIdx.x;                 // B_*ND_
  const int bz = blk >> 10, d = blk & 1023;
  const float4* src = (const float4*)(x + ((size_t)bz * N_ + b_idx[d]) * C_);
  float4* dst = (float4*)(xm + ((size_t)bz * ND_ + d) * C_);
  dst[threadIdx.x] = src[threadIdx.x];
}

__global__ __launch_bounds__(256) void k_merge_add(const float* __restrict__ x,
                                                   const int* __restrict__ a_idx,
                                                   const int* __restrict__ node_idx,
                                                   float* __restrict__ xm) {
  const int blk = blockIdx.x;                 // B_*NA_ = bz*NA_+i
  const int bz = blk / NA_, i = blk % NA_;
  const int nd = node_idx[blk];
  const float* src = x + ((size_t)bz * N_ + a_idx[i]) * C_;
  float* dst = xm + ((size_t)bz * ND_ + nd) * C_;
  const int c0 = threadIdx.x * 4;
  const float4 v = *(const float4*)(src + c0);
  atomicAdd(&dst[c0 + 0], v.x);
  atomicAdd(&dst[c0 + 1], v.y);
  atomicAdd(&dst[c0 + 2], v.z);
  atomicAdd(&dst[c0 + 3], v.w);
}

__global__ __launch_bounds__(256) void k_merge_scale(float* __restrict__ xm,
                                                     const int* __restrict__ cnt) {
  const int blk = blockIdx.x;                 // B_*ND_
  const float s = 1.0f + (float)cnt[blk];
  float4* p = (float4*)(xm + (size_t)blk * C_);
  float4 v = p[threadIdx.x];
  v.x /= s; v.y /= s; v.z /= s; v.w /= s;
  p[threadIdx.x] = v;
}

// ---------------------------------------------------------------------------
// K10: qkv GEMM, 128x128 tile, 8x8 per thread, BK=8.
// ---------------------------------------------------------------------------
__global__ __launch_bounds__(256) void k_qkv(const float* __restrict__ xm,
                                             const float* __restrict__ Wqkv,
                                             float* __restrict__ qkvm) {
  __shared__ __align__(16) float As[8][132];
  __shared__ __align__(16) float Bs[8][132];
  const int nb = blockIdx.x;   // 24
  const int mb = blockIdx.y;   // 32
  const int tid = threadIdx.x;
  const int tx = tid & 15, ty = tid >> 4;
  const int lr = tid >> 1;            // 0..127
  const int lkc = (tid & 1) * 4;      // 0 or 4
  const float* __restrict__ ar = xm + (size_t)(mb * 128 + lr) * C_ + lkc;
  const float* __restrict__ br = Wqkv + (size_t)(nb * 128 + lr) * C_ + lkc;
  float acc[8][8] = {};
  for (int k0 = 0; k0 < C_; k0 += 8) {
    const float4 av = *(const float4*)(ar + k0);
    const float4 bv = *(const float4*)(br + k0);
    __syncthreads();
    As[lkc + 0][lr] = av.x; As[lkc + 1][lr] = av.y;
    As[lkc + 2][lr] = av.z; As[lkc + 3][lr] = av.w;
    Bs[lkc + 0][lr] = bv.x; Bs[lkc + 1][lr] = bv.y;
    Bs[lkc + 2][lr] = bv.z; Bs[lkc + 3][lr] = bv.w;
    __syncthreads();
#pragma unroll
    for (int k = 0; k < 8; k++) {
      float a_[8], b_[8];
      *(float4*)&a_[0] = *(const float4*)&As[k][ty * 8];
      *(float4*)&a_[4] = *(const float4*)&As[k][ty * 8 + 4];
      *(float4*)&b_[0] = *(const float4*)&Bs[k][tx * 8];
      *(float4*)&b_[4] = *(const float4*)&Bs[k][tx * 8 + 4];
#pragma unroll
      for (int i = 0; i < 8; i++)
#pragma unroll
        for (int j = 0; j < 8; j++) acc[i][j] = fmaf(a_[i], b_[j], acc[i][j]);
    }
  }
  const int n0 = nb * 128 + tx * 8;
  const int w = n0 >> 10, h = (n0 >> 6) & 15, dc = n0 & 63;   // 8 cols within 1 head
#pragma unroll
  for (int i = 0; i < 8; i++) {
    const int m = mb * 128 + ty * 8 + i;
    const int bb = m >> 10, t = m & 1023;
    float* dst = qkvm + (((size_t)(bb * 3 + w) * 16 + h) * 1024 + t) * 64 + dc;
    *(float4*)dst       = make_float4(acc[i][0], acc[i][1], acc[i][2], acc[i][3]);
    *(float4*)(dst + 4) = make_float4(acc[i][4], acc[i][5], acc[i][6], acc[i][7]);
  }
}

// ---------------------------------------------------------------------------
// K11: flash attention. R0 body (88 VGPR class) + psT aliased onto ksT:
//  - kps = ksT during QK^T, swizzled psT during PV (saves 16.6 KB ->
//    LDS 50,432 B -> 3 blocks/CU). Costs one extra barrier per tile.
//  - psT XOR swizzle col' = ty*4 + (i ^ (tx&3)): epilogue writes conflict-free;
//    decode in PV is a compile-time component permute.
//  - NO register prefetch, mi/li stay in LDS: keeps VGPR <= 128 class
//    (R1 lesson: 132 VGPR halved occupancy).
// Arithmetic order identical to R0 -> bitwise same output.
// ---------------------------------------------------------------------------
__global__ __launch_bounds__(256) void k_attn(const float* __restrict__ qkvm,
                                              float* __restrict__ om) {
  __shared__ float qsT[64][65];   // [d][qtok]
  __shared__ float kps[64][65];   // phase1: ksT [d][ktok]; phase2: psT swizzled
  __shared__ float vs[64][65];    // [ktok][d]
  __shared__ float mi[64], li[64];
  const int qb = blockIdx.x, h = blockIdx.y, bz = blockIdx.z;
  const int tid = threadIdx.x;
  const int tx = tid & 15, ty = tid >> 4;
  const float* __restrict__ qp = qkvm + (((size_t)(bz * 3 + 0) * 16 + h) * 1024) * 64;
  const float* __restrict__ kp = qkvm + (((size_t)(bz * 3 + 1) * 16 + h) * 1024) * 64;
  const float* __restrict__ vp = qkvm + (((size_t)(bz * 3 + 2) * 16 + h) * 1024) * 64;
  const int lr = tid >> 2, lc = (tid & 3) * 16;
  {
    const float4* src = (const float4*)(qp + (size_t)(qb * 64 + lr) * 64 + lc);
#pragma unroll
    for (int j = 0; j < 4; j++) {
      const float4 v4 = src[j];
      qsT[lc + j * 4 + 0][lr] = v4.x * 0.125f;
      qsT[lc + j * 4 + 1][lr] = v4.y * 0.125f;
      qsT[lc + j * 4 + 2][lr] = v4.z * 0.125f;
      qsT[lc + j * 4 + 3][lr] = v4.w * 0.125f;
    }
  }
  if (tid < 64) { mi[tid] = -INFINITY; li[tid] = 0.0f; }
  float o[4][4] = {};
  float mnew[4], alpha[4], psum[4];
  for (int kt = 0; kt < 16; kt++) {
    __syncthreads();          // prev PV reads of kps/vs complete
    {
      const float4* ksrc = (const float4*)(kp + (size_t)(kt * 64 + lr) * 64 + lc);
      const float4* vsrc = (const float4*)(vp + (size_t)(kt * 64 + lr) * 64 + lc);
#pragma unroll
      for (int j = 0; j < 4; j++) {
        const float4 kv = ksrc[j], vv = vsrc[j];
        kps[lc + j * 4 + 0][lr] = kv.x; kps[lc + j * 4 + 1][lr] = kv.y;
        kps[lc + j * 4 + 2][lr] = kv.z; kps[lc + j * 4 + 3][lr] = kv.w;
        vs[lr][lc + j * 4 + 0] = vv.x; vs[lr][lc + j * 4 + 1] = vv.y;
        vs[lr][lc + j * 4 + 2] = vv.z; vs[lr][lc + j * 4 + 3] = vv.w;
      }
    }
    __syncthreads();          // staging visible
    // QK^T: reads qsT + kps(=ksT)
    float sacc[4][4] = {};
#pragma unroll 4
    for (int c = 0; c < 64; c++) {
      const float4 a4 = *(const float4*)&qsT[c][ty * 4];
      const float4 b4 = *(const float4*)&kps[c][tx * 4];
      const float a_[4] = {a4.x, a4.y, a4.z, a4.w};
      const float b_[4] = {b4.x, b4.y, b4.z, b4.w};
#pragma unroll
      for (int i = 0; i < 4; i++)
#pragma unroll
        for (int j = 0; j < 4; j++) sacc[i][j] = fmaf(a_[i], b_[j], sacc[i][j]);
    }
    // online softmax (mi/li in LDS as R0; exp'd P kept in regs across barrier)
#pragma unroll
    for (int i = 0; i < 4; i++) {
      float tmax = fmaxf(fmaxf(sacc[i][0], sacc[i][1]), fmaxf(sacc[i][2], sacc[i][3]));
#pragma unroll
      for (int off = 8; off; off >>= 1) tmax = fmaxf(tmax, __shfl_xor(tmax, off, 16));
      const float mold = mi[ty * 4 + i];
      const float mn = fmaxf(mold, tmax);
      mnew[i] = mn;
      alpha[i] = expf(mold - mn);
      float s_ = 0.0f;
#pragma unroll
      for (int j = 0; j < 4; j++) { sacc[i][j] = expf(sacc[i][j] - mn); s_ += sacc[i][j]; }
#pragma unroll
      for (int off = 8; off; off >>= 1) s_ += __shfl_xor(s_, off, 16);
      psum[i] = s_;
    }
    __syncthreads();          // all QK reads of kps done; safe to overwrite as psT
    // write P^T swizzled: row r=tx*4+j, col = ty*4 + (i ^ (tx&3))
    {
      const int sw = tx & 3;
#pragma unroll
      for (int i = 0; i < 4; i++) {
        const int cc = ty * 4 + (i ^ sw);
#pragma unroll
        for (int j = 0; j < 4; j++) kps[tx * 4 + j][cc] = sacc[i][j];
      }
    }
    if (tx == 0) {
#pragma unroll
      for (int i = 0; i < 4; i++) {
        mi[ty * 4 + i] = mnew[i];
        li[ty * 4 + i] = li[ty * 4 + i] * alpha[i] + psum[i];
      }
    }
    __syncthreads();          // psT + mi/li visible
    // rescale o
#pragma unroll
    for (int i = 0; i < 4; i++)
#pragma unroll
      for (int j = 0; j < 4; j++) o[i][j] *= alpha[i];
    // PV: reads kps(=psT, swizzled) + vs
    for (int g = 0; g < 4; g++) {
#pragma unroll
      for (int u = 0; u < 16; u++) {
        const int d2 = g * 16 + u;
        const int s2 = (u >> 2) & 3;          // == (d2>>2)&3, compile-time
        const float4 p4 = *(const float4*)&kps[d2][ty * 4];
        const float4 v4 = *(const float4*)&vs[d2][tx * 4];
        const float pp[4] = {p4.x, p4.y, p4.z, p4.w};
        const float pr[4] = {pp[0 ^ s2], pp[1 ^ s2], pp[2 ^ s2], pp[3 ^ s2]};
        const float vr[4] = {v4.x, v4.y, v4.z, v4.w};
#pragma unroll
        for (int i = 0; i < 4; i++)
#pragma unroll
          for (int j = 0; j < 4; j++) o[i][j] = fmaf(pr[i], vr[j], o[i][j]);
      }
    }
  }
  __syncthreads();
#pragma unroll
  for (int i = 0; i < 4; i++) {
    const float inv = 1.0f / li[ty * 4 + i];
    const int t = qb * 64 + ty * 4 + i;
    const float4 st = make_float4(o[i][0] * inv, o[i][1] * inv, o[i][2] * inv, o[i][3] * inv);
    *(float4*)(om + ((size_t)bz * ND_ + t) * C_ + h * 64 + tx * 4) = st;
  }
}

// ---------------------------------------------------------------------------
// K12: proj GEMM, 128x128 tile, 8x8 per thread, BK=8. ym = om@Wp^T + bp
// ---------------------------------------------------------------------------
__global__ __launch_bounds__(256) void k_proj(const float* __restrict__ om,
                                              const float* __restrict__ Wp,
                                              const float* __restrict__ bp,
                                              float* __restrict__ ym) {
  __shared__ __align__(16) float As[8][132];
  __shared__ __align__(16) float Bs[8][132];
  const int nb = blockIdx.x;   // 8
  const int mb = blockIdx.y;   // 32
  const int tid = threadIdx.x;
  const int tx = tid & 15, ty = tid >> 4;
  const int lr = tid >> 1;
  const int lkc = (tid & 1) * 4;
  const float* __restrict__ ar = om + (size_t)(mb * 128 + lr) * C_ + lkc;
  const float* __restrict__ br = Wp + (size_t)(nb * 128 + lr) * C_ + lkc;
  float acc[8][8] = {};
  for (int k0 = 0; k0 < C_; k0 += 8) {
    const float4 av = *(const float4*)(ar + k0);
    const float4 bv = *(const float4*)(br + k0);
    __syncthreads();
    As[lkc + 0][lr] = av.x; As[lkc + 1][lr] = av.y;
    As[lkc + 2][lr] = av.z; As[lkc + 3][lr] = av.w;
    Bs[lkc + 0][lr] = bv.x; Bs[lkc + 1][lr] = bv.y;
    Bs[lkc + 2][lr] = bv.z; Bs[lkc + 3][lr] = bv.w;
    __syncthreads();
#pragma unroll
    for (int k = 0; k < 8; k++) {
      float a_[8], b_[8];
      *(float4*)&a_[0] = *(const float4*)&As[k][ty * 8];
      *(float4*)&a_[4] = *(const float4*)&As[k][ty * 8 + 4];
      *(float4*)&b_[0] = *(const float4*)&Bs[k][tx * 8];
      *(float4*)&b_[4] = *(const float4*)&Bs[k][tx * 8 + 4];
#pragma unroll
      for (int i = 0; i < 8; i++)
#pragma unroll
        for (int j = 0; j < 8; j++) acc[i][j] = fmaf(a_[i], b_[j], acc[i][j]);
    }
  }
  const int n0 = nb * 128 + tx * 8;
  const float4 b0 = *(const float4*)(bp + n0);
  const float4 b1 = *(const float4*)(bp + n0 + 4);
#pragma unroll
  for (int i = 0; i < 8; i++) {
    const int m = mb * 128 + ty * 8 + i;
    float* dst = ym + (size_t)m * C_ + n0;
    *(float4*)dst       = make_float4(acc[i][0] + b0.x, acc[i][1] + b0.y,
                                      acc[i][2] + b0.z, acc[i][3] + b0.w);
    *(float4*)(dst + 4) = make_float4(acc[i][4] + b1.x, acc[i][5] + b1.y,
                                      acc[i][6] + b1.z, acc[i][7] + b1.w);
  }
}

// K13: scatter merged rows back to all 4096 tokens
__global__ __launch_bounds__(256) void k_unmerge(const float* __restrict__ ym,
                                                 const int* __restrict__ rowmap,
                                                 float* __restrict__ out) {
  const int blk = blockIdx.x;                 // B_*N_
  const int bz = blk >> 12;
  const int r = rowmap[blk];
  const float4* src = (const float4*)(ym + ((size_t)bz * ND_ + r) * C_);
  float4* dst = (float4*)(out + (size_t)blk * C_);
  dst[threadIdx.x] = src[threadIdx.x];
}

// ---------------------------------------------------------------------------
extern "C" void kernel_launch(void* const* d_in, const int* in_sizes, int n_in,
                              void* d_out, int out_size, void* d_ws, size_t ws_size,
                              hipStream_t stream) {
  const float* x    = (const float*)d_in[0];
  const float* Wqkv = (const float*)d_in[1];
  const float* Wp   = (const float*)d_in[2];
  const float* bp   = (const float*)d_in[3];
  char* ws = (char*)d_ws;
  double* dinv    = (double*)(ws + 0);          //  131072 B
  int*   b_idx    = (int*)(ws + 131072);        //    4096 B
  int*   a_idx    = (int*)(ws + 135168);        //   12288 B
  int*   node_idx = (int*)(ws + 147456);        //   49152 B
  int*   cnt      = (int*)(ws + 196608);        //   16384 B
  int*   rowmap   = (int*)(ws + 212992);        //   65536 B
  int*   flagr    = (int*)(ws + 278528);        //   49152 B
  float* pv1      = (float*)(ws + 327680);      //  786432 B
  int*   pi1      = (int*)(ws + 1114112);       //  786432 B
  float* pv2      = (float*)(ws + 1900544);     //  786432 B
  int*   pi2      = (int*)(ws + 2686976);       //  786432 B
  // xh/xl: bf16 hi/lo of normalized x. Live only from k_prep to k_scores_mfma;
  // region is later overwritten by xm (3,473,408) and qkvm (20,250,624) --
  // stream-ordered, so safe. Total workspace footprint unchanged (87.36 MB).
  unsigned short* xh = (unsigned short*)(ws + 3473408);    // 33,554,432 B
  unsigned short* xl = (unsigned short*)(ws + 37027840);   // 33,554,432 B (ends 70,582,272)
  float* xm       = (float*)(ws + 3473408);    // 16.78 MB (aliases xh; written after scores)
  float* qkvm     = (float*)(ws + 20250624);   // 50.33 MB (aliases xh tail + xl)
  float* om       = (float*)(ws + 70582272);   // 16.78 MB
  float* ym       = xm;                        // reuse (xm consumed by k_qkv)
  float* out      = (float*)d_out;

  hipMemsetAsync(cnt, 0, B_ * ND_ * sizeof(int), stream);
  k_init_indices<<<1, 1024, 0, stream>>>(b_idx, a_idx);
  k_row_norms<<<B_ * N_, 256, 0, stream>>>(x, dinv);
  k_prep<<<B_ * N_, 256, 0, stream>>>(x, dinv, xh, xl);
  k_scores_mfma<<<dim3(16, 48, B_), 256, 0, stream>>>(xh, xl, a_idx, b_idx, pv1, pi1, pv2, pi2);
  k_finalize<<<(B_ * NA_) / 256, 256, 0, stream>>>(pv1, pi1, pv2, pi2, node_idx, flagr);
  k_recheck<<<B_ * NA_, 256, 0, stream>>>(x, dinv, a_idx, b_idx, pv1, pi1, pv2, pi2, flagr, node_idx);
  k_counts_rowmap<<<(B_ * N_) / 256, 256, 0, stream>>>(a_idx, b_idx, node_idx, cnt, rowmap);
  k_merge_init<<<B_ * ND_, 256, 0, stream>>>(x, b_idx, xm);
  k_merge_add<<<B_ * NA_, 256, 0, stream>>>(x, a_idx, node_idx, xm);
  k_merge_scale<<<B_ * ND_, 256, 0, stream>>>(xm, cnt);
  k_qkv<<<dim3(24, 32), 256, 0, stream>>>(xm, Wqkv, qkvm);
  k_attn<<<dim3(16, 16, B_), 256, 0, stream>>>(qkvm, om);
  k_proj<<<dim3(8, 32), 256, 0, stream>>>(om, Wp, bp, ym);
  k_unmerge<<<B_ * N_, 256, 0, stream>>>(ym, rowmap, out);
}

// Round 4
// 1282.213 us; speedup vs baseline: 1.3154x; 1.2057x over previous
//
#include <hip/hip_runtime.h>
#include <cmath>

// Problem constants (B,N,DIM,HEADS)=(4,4096,1024,16), SX=SY=2, ratio .9
#define B_  4
#define N_  4096
#define C_  1024
#define H_  16
#define D_  64
#define ND_ 1024   // num dst tokens (one per 2x2 block)
#define NA_ 3072   // num src (a) tokens
// r = min(3072, int(4096*0.9)) = 3072  => unm empty, sort permutation cancels.

typedef __attribute__((ext_vector_type(8))) short short8v;
typedef __attribute__((ext_vector_type(4))) float f32x4;

// ---------------------------------------------------------------------------
// threefry2x32 (20 rounds), returns BOTH output words.
// ---------------------------------------------------------------------------
__device__ inline void tf2x32(unsigned k0, unsigned k1, unsigned x0, unsigned x1,
                              unsigned& o0, unsigned& o1) {
  const unsigned ks2 = 0x1BD11BDAu ^ k0 ^ k1;
  x0 += k0; x1 += k1;
#define RND_(r) { x0 += x1; x1 = (x1 << (r)) | (x1 >> (32 - (r))); x1 ^= x0; }
  RND_(13) RND_(15) RND_(26) RND_(6)
  x0 += k1;  x1 += ks2 + 1u;
  RND_(17) RND_(29) RND_(16) RND_(24)
  x0 += ks2; x1 += k0 + 2u;
  RND_(13) RND_(15) RND_(26) RND_(6)
  x0 += k0;  x1 += k1 + 3u;
  RND_(17) RND_(29) RND_(16) RND_(24)
  x0 += k1;  x1 += ks2 + 4u;
  RND_(13) RND_(15) RND_(26) RND_(6)
  x0 += ks2; x1 += k0 + 5u;
#undef RND_
  o0 = x0; o1 = x1;
}

// ---------------------------------------------------------------------------
// K1 (VERIFIED r7): jax.random.randint(key(33),(32,32),0,4)
// ---------------------------------------------------------------------------
__global__ __launch_bounds__(1024) void k_init_indices(int* __restrict__ b_idx,
                                                       int* __restrict__ a_idx) {
  __shared__ unsigned char randk[1024];
  __shared__ int wtot[16], wpre[16];
  const int tid = threadIdx.x;
  {
    unsigned c0, c1;
    tf2x32(0u, 33u, 0u, 1u, c0, c1);                 // k2 = split(key)[1]
    unsigned d0, d1;
    tf2x32(c0, c1, 0u, (unsigned)tid, d0, d1);       // random_bits element p
    randk[tid] = (unsigned char)((d0 ^ d1) & 3u);    // xor-fold, % span
  }
  __syncthreads();
  const int base_t = tid * 4;
  int f[4]; int cnt = 0;
#pragma unroll
  for (int j = 0; j < 4; j++) {
    const int t = base_t + j;
    const int y = t >> 6, xc = t & 63;
    const int bi = (y >> 1) * 32 + (xc >> 1);
    const int k  = (y & 1) * 2 + (xc & 1);
    f[j] = (randk[bi] == (unsigned char)k) ? 1 : 0;
    cnt += f[j];
  }
  const int lane = tid & 63, wave = tid >> 6;
  int incl = cnt;
#pragma unroll
  for (int off = 1; off < 64; off <<= 1) {
    int nb = __shfl_up(incl, off, 64);
    if (lane >= off) incl += nb;
  }
  if (lane == 63) wtot[wave] = incl;
  __syncthreads();
  if (tid == 0) { int s = 0; for (int w = 0; w < 16; w++) { wpre[w] = s; s += wtot[w]; } }
  __syncthreads();
  int P = wpre[wave] + (incl - cnt);   // #dst strictly before base_t
#pragma unroll
  for (int j = 0; j < 4; j++) {
    const int t = base_t + j;
    if (f[j]) { b_idx[P] = t; P++; }
    else      { a_idx[t - P] = t; }
  }
}

// ---------------------------------------------------------------------------
// K2: per-token inverse L2 norm of x, fp64
// ---------------------------------------------------------------------------
__global__ __launch_bounds__(256) void k_row_norms(const float* __restrict__ x,
                                                   double* __restrict__ dinv) {
  const int row = blockIdx.x;                 // B_*N_
  const float* xr = x + (size_t)row * C_;
  const int tid = threadIdx.x;
  float4 v = ((const float4*)xr)[tid];
  double s = (double)v.x * (double)v.x + (double)v.y * (double)v.y +
             (double)v.z * (double)v.z + (double)v.w * (double)v.w;
#pragma unroll
  for (int off = 32; off; off >>= 1) s += __shfl_down(s, off, 64);
  __shared__ double wsum[4];
  if ((tid & 63) == 0) wsum[tid >> 6] = s;
  __syncthreads();
  if (tid == 0) {
    double t = wsum[0] + wsum[1] + wsum[2] + wsum[3];
    dinv[row] = 1.0 / sqrt(t);
  }
}

// ---------------------------------------------------------------------------
// bf16 split helpers (RTNE)
// ---------------------------------------------------------------------------
__device__ inline unsigned short f2bf_rtne(float f) {
  const unsigned u = __float_as_uint(f);
  return (unsigned short)((u + 0x7FFFu + ((u >> 16) & 1u)) >> 16);
}

__device__ inline void split8(const float* f, short8v& h8, short8v& l8) {
#pragma unroll
  for (int j = 0; j < 8; j++) {
    const unsigned short hv = f2bf_rtne(f[j]);
    const float fh = __uint_as_float((unsigned)hv << 16);
    const unsigned short lv = f2bf_rtne(f[j] - fh);
    h8[j] = (short)hv; l8[j] = (short)lv;
  }
}

// ---------------------------------------------------------------------------
// K2b: normalized rows split into bf16 hi + bf16 lo (RTNE), for MFMA scores.
// ---------------------------------------------------------------------------
__global__ __launch_bounds__(256) void k_prep(const float* __restrict__ x,
                                              const double* __restrict__ dinv,
                                              unsigned short* __restrict__ xh,
                                              unsigned short* __restrict__ xl) {
  const int row = blockIdx.x;                 // B_*N_
  const float ia = (float)dinv[row];
  const float4 v = ((const float4*)(x + (size_t)row * C_))[threadIdx.x];
  float f[4] = {v.x * ia, v.y * ia, v.z * ia, v.w * ia};
  unsigned h[4], l[4];
#pragma unroll
  for (int j = 0; j < 4; j++) {
    h[j] = f2bf_rtne(f[j]);
    const float fh = __uint_as_float(h[j] << 16);
    l[j] = f2bf_rtne(f[j] - fh);
  }
  const size_t o = (size_t)row * C_ + threadIdx.x * 4;
  uint2 ph, pl;
  ph.x = h[0] | (h[1] << 16); ph.y = h[2] | (h[3] << 16);
  pl.x = l[0] | (l[1] << 16); pl.y = l[2] | (l[3] << 16);
  *(uint2*)&xh[o] = ph;
  *(uint2*)&xl[o] = pl;
}

// top-2 merge tracking both indices
__device__ inline void top2m(float& v1, int& i1, float& v2, int& i2,
                             float ov1, int oi1, float ov2, int oi2) {
  if (ov1 > v1 || (ov1 == v1 && oi1 < i1)) {
    if (v1 > ov2 || (v1 == ov2 && i1 < oi2)) { v2 = v1; i2 = i1; }
    else { v2 = ov2; i2 = oi2; }
    v1 = ov1; i1 = oi1;
  } else if (ov1 > v2 || (ov1 == v2 && oi1 < i2)) {
    v2 = ov1; i2 = oi1;
  }
}

// ---------------------------------------------------------------------------
// K3: scores via bf16x3 MFMA (verified R2). 64x64 tile, top-2 epilogue.
// ---------------------------------------------------------------------------
__global__ __launch_bounds__(256) void k_scores_mfma(
    const unsigned short* __restrict__ xh, const unsigned short* __restrict__ xl,
    const int* __restrict__ a_idx, const int* __restrict__ b_idx,
    float* __restrict__ pv1, int* __restrict__ pi1,
    float* __restrict__ pv2, int* __restrict__ pi2) {
  __shared__ unsigned short Ah[64][40], Al[64][40], Bh[64][40], Bl[64][40];
  __shared__ float mv1[64][2], mv2[64][2];
  __shared__ int   mi1[64][2], mi2[64][2];
  const int bz = blockIdx.z, cb = blockIdx.x, sb = blockIdx.y;
  const int tid = threadIdx.x;
  const int srow = tid >> 2, sq = tid & 3;       // staging row / 16B chunk
  const int ga = a_idx[sb * 64 + srow];
  const int gb = b_idx[cb * 64 + srow];
  const size_t abase = ((size_t)bz * N_ + ga) * C_;
  const size_t bbase = ((size_t)bz * N_ + gb) * C_;
  const int wv = tid >> 6, lane = tid & 63;
  const int wr = wv >> 1, wc = wv & 1;
  const int fr = lane & 15, fg = lane >> 4;      // frag row-in-16 / k-group
  f32x4 acc[2][2] = {};
  for (int k0 = 0; k0 < C_; k0 += 32) {
    __syncthreads();
    *(uint4*)&Ah[srow][sq * 8] = *(const uint4*)(xh + abase + k0 + sq * 8);
    *(uint4*)&Al[srow][sq * 8] = *(const uint4*)(xl + abase + k0 + sq * 8);
    *(uint4*)&Bh[srow][sq * 8] = *(const uint4*)(xh + bbase + k0 + sq * 8);
    *(uint4*)&Bl[srow][sq * 8] = *(const uint4*)(xl + bbase + k0 + sq * 8);
    __syncthreads();
    short8v ah[2], al[2], bh[2], bl[2];
#pragma unroll
    for (int i = 0; i < 2; i++) {
      const int ra = wr * 32 + i * 16 + fr;
      const int rb = wc * 32 + i * 16 + fr;
      ah[i] = *(const short8v*)&Ah[ra][fg * 8];
      al[i] = *(const short8v*)&Al[ra][fg * 8];
      bh[i] = *(const short8v*)&Bh[rb][fg * 8];
      bl[i] = *(const short8v*)&Bl[rb][fg * 8];
    }
#pragma unroll
    for (int i = 0; i < 2; i++)
#pragma unroll
      for (int j = 0; j < 2; j++) {
        acc[i][j] = __builtin_amdgcn_mfma_f32_16x16x32_bf16(al[i], bh[j], acc[i][j], 0, 0, 0);
        acc[i][j] = __builtin_amdgcn_mfma_f32_16x16x32_bf16(ah[i], bl[j], acc[i][j], 0, 0, 0);
        acc[i][j] = __builtin_amdgcn_mfma_f32_16x16x32_bf16(ah[i], bh[j], acc[i][j], 0, 0, 0);
      }
  }
  // top-2 epilogue. D layout: col = lane&15, row = (lane>>4)*4 + reg (m89).
#pragma unroll
  for (int i = 0; i < 2; i++) {
#pragma unroll
    for (int r = 0; r < 4; r++) {
      const float va = acc[i][0][r]; const int ca = cb * 64 + wc * 32 + fr;
      const float vb = acc[i][1][r]; const int cbg = ca + 16;
      float v1, v2; int i1, i2;
      if (vb > va) { v1 = vb; i1 = cbg; v2 = va; i2 = ca; }
      else         { v1 = va; i1 = ca;  v2 = vb; i2 = cbg; }
#pragma unroll
      for (int off = 8; off; off >>= 1) {
        const float ov1 = __shfl_xor(v1, off, 16);
        const int   oi1 = __shfl_xor(i1, off, 16);
        const float ov2 = __shfl_xor(v2, off, 16);
        const int   oi2 = __shfl_xor(i2, off, 16);
        top2m(v1, i1, v2, i2, ov1, oi1, ov2, oi2);
      }
      if (fr == 0) {
        const int rl = wr * 32 + i * 16 + fg * 4 + r;
        mv1[rl][wc] = v1; mi1[rl][wc] = i1; mv2[rl][wc] = v2; mi2[rl][wc] = i2;
      }
    }
  }
  __syncthreads();
  if (tid < 64) {
    float v1 = mv1[tid][0], v2 = mv2[tid][0];
    int   i1 = mi1[tid][0], i2 = mi2[tid][0];
    top2m(v1, i1, v2, i2, mv1[tid][1], mi1[tid][1], mv2[tid][1], mi2[tid][1]);
    const int s = sb * 64 + tid;
    const size_t o = ((size_t)bz * NA_ + s) * 16 + cb;
    pv1[o] = v1; pi1[o] = i1; pv2[o] = v2; pi2[o] = i2;
  }
}

// K4: merge 16 per-tile partials -> node_idx + near-tie flag
__global__ __launch_bounds__(256) void k_finalize(
    const float* __restrict__ pv1, const int* __restrict__ pi1,
    const float* __restrict__ pv2, const int* __restrict__ pi2,
    int* __restrict__ node_idx, int* __restrict__ flagr) {
  const int r = blockIdx.x * 256 + threadIdx.x;   // [0, B_*NA_)
  if (r >= B_ * NA_) return;
  size_t o = (size_t)r * 16;
  float v1 = pv1[o]; int i1 = pi1[o]; float v2 = pv2[o]; int i2 = pi2[o];
  for (int cb = 1; cb < 16; cb++)
    top2m(v1, i1, v2, i2, pv1[o + cb], pi1[o + cb], pv2[o + cb], pi2[o + cb]);
  node_idx[r] = i1;
  flagr[r] = (v1 - v2 < 1e-3f) ? 1 : 0;  // unflagged => true gap > 9e-4 => exact
}

// ---------------------------------------------------------------------------
// K5: candidate-based fp64 recheck for flagged rows.
// ---------------------------------------------------------------------------
__global__ __launch_bounds__(256) void k_recheck(
    const float* __restrict__ x, const double* __restrict__ dinv,
    const int* __restrict__ a_idx, const int* __restrict__ b_idx,
    const float* __restrict__ pv1, const int* __restrict__ pi1,
    const float* __restrict__ pv2, const int* __restrict__ pi2,
    const int* __restrict__ flagr, int* __restrict__ node_idx) {
  const int r = blockIdx.x;                 // bz*NA_ + s
  if (!flagr[r]) return;
  const int bz = r / NA_, s = r % NA_;
  __shared__ double arow[C_];
  __shared__ int cand[1088];
  __shared__ int ncand;
  __shared__ float v1s[16];
  const int tid = threadIdx.x;
  const int ga = a_idx[s];
  const double ia = dinv[bz * N_ + ga];
  const float* xa = x + ((size_t)bz * N_ + ga) * C_;
  for (int c = tid; c < C_; c += 256) arow[c] = (double)xa[c] * ia;
  const size_t o = (size_t)r * 16;
  if (tid < 16) v1s[tid] = pv1[o + tid];
  if (tid == 0) ncand = 0;
  __syncthreads();
  float v1g = v1s[0];
#pragma unroll
  for (int cb = 1; cb < 16; cb++) v1g = fmaxf(v1g, v1s[cb]);
  if (tid < 16) {
    const float tv1 = pv1[o + tid], tv2 = pv2[o + tid];
    if (tv2 >= v1g - 2.5e-4f) {
      const int base = atomicAdd(&ncand, 64);
      for (int j = 0; j < 64; j++) cand[base + j] = tid * 64 + j;
    } else {
      if (tv1 >= v1g - 1e-3f) { cand[atomicAdd(&ncand, 1)] = pi1[o + tid]; }
      if (tv2 >= v1g - 1e-3f) { cand[atomicAdd(&ncand, 1)] = pi2[o + tid]; }
    }
  }
  __syncthreads();
  const int nc = ncand;
  const int lane = tid & 63, wave = tid >> 6;
  double bv = -1e300; int bi = 1 << 30;
  for (int ci = wave; ci < nc; ci += 4) {
    const int d = cand[ci];
    const int gb = b_idx[d];
    const double ib = dinv[bz * N_ + gb];
    const float* xb = x + ((size_t)bz * N_ + gb) * C_;
    double sum = 0.0;
    for (int c = lane; c < C_; c += 64) sum += arow[c] * ((double)xb[c] * ib);
#pragma unroll
    for (int off = 32; off; off >>= 1) sum += __shfl_xor(sum, off, 64);
    if (sum > bv || (sum == bv && d < bi)) { bv = sum; bi = d; }
  }
  __shared__ double bvs[4]; __shared__ int bis[4];
  if (lane == 0) { bvs[wave] = bv; bis[wave] = bi; }
  __syncthreads();
  if (tid == 0) {
    for (int w = 1; w < 4; w++)
      if (bvs[w] > bv || (bvs[w] == bv && bis[w] < bi)) { bv = bvs[w]; bi = bis[w]; }
    node_idx[r] = bi;
  }
}

// K6: counts per dst + token->merged-row map
__global__ __launch_bounds__(256) void k_counts_rowmap(
    const int* __restrict__ a_idx, const int* __restrict__ b_idx,
    const int* __restrict__ node_idx, int* __restrict__ cnt,
    int* __restrict__ rowmap) {
  const int i = blockIdx.x * 256 + threadIdx.x;   // [0, B_*N_)
  if (i >= B_ * N_) return;
  const int bz = i >> 12, j = i & 4095;
  if (j < NA_) {
    const int nd = node_idx[bz * NA_ + j];
    atomicAdd(&cnt[bz * ND_ + nd], 1);
    rowmap[bz * N_ + a_idx[j]] = nd;
  } else {
    const int d = j - NA_;
    rowmap[bz * N_ + b_idx[d]] = d;
  }
}

// K7/K8/K9: merge x into xm
__global__ __launch_bounds__(256) void k_merge_init(const float* __restrict__ x,
                                                    const int* __restrict__ b_idx,
                                                    float* __restrict__ xm) {
  const int blk = blockIdx.x;                 // B_*ND_
  const int bz = blk >> 10, d = blk & 1023;
  const float4* src = (const float4*)(x + ((size_t)bz * N_ + b_idx[d]) * C_);
  float4* dst = (float4*)(xm + ((size_t)bz * ND_ + d) * C_);
  dst[threadIdx.x] = src[threadIdx.x];
}

__global__ __launch_bounds__(256) void k_merge_add(const float* __restrict__ x,
                                                   const int* __restrict__ a_idx,
                                                   const int* __restrict__ node_idx,
                                                   float* __restrict__ xm) {
  const int blk = blockIdx.x;                 // B_*NA_ = bz*NA_+i
  const int bz = blk / NA_, i = blk % NA_;
  const int nd = node_idx[blk];
  const float* src = x + ((size_t)bz * N_ + a_idx[i]) * C_;
  float* dst = xm + ((size_t)bz * ND_ + nd) * C_;
  const int c0 = threadIdx.x * 4;
  const float4 v = *(const float4*)(src + c0);
  atomicAdd(&dst[c0 + 0], v.x);
  atomicAdd(&dst[c0 + 1], v.y);
  atomicAdd(&dst[c0 + 2], v.z);
  atomicAdd(&dst[c0 + 3], v.w);
}

__global__ __launch_bounds__(256) void k_merge_scale(float* __restrict__ xm,
                                                     const int* __restrict__ cnt) {
  const int blk = blockIdx.x;                 // B_*ND_
  const float s = 1.0f + (float)cnt[blk];
  float4* p = (float4*)(xm + (size_t)blk * C_);
  float4 v = p[threadIdx.x];
  v.x /= s; v.y /= s; v.z /= s; v.w /= s;
  p[threadIdx.x] = v;
}

// ---------------------------------------------------------------------------
// K10: qkv GEMM, 128x128 tile, 8x8 per thread, BK=8.
// Epilogue writes bf16 hi/lo pairs (gh/gl) for MFMA attention:
//   w=0 (Q): scaled by 0.125, [tok][64] layout
//   w=1 (K): [tok][64] layout
//   w=2 (V): TRANSPOSED [64 d][1024 tok] layout (free transpose at store)
// ---------------------------------------------------------------------------
__global__ __launch_bounds__(256) void k_qkv(const float* __restrict__ xm,
                                             const float* __restrict__ Wqkv,
                                             unsigned short* __restrict__ gh,
                                             unsigned short* __restrict__ gl) {
  __shared__ __align__(16) float As[8][132];
  __shared__ __align__(16) float Bs[8][132];
  const int nb = blockIdx.x;   // 24
  const int mb = blockIdx.y;   // 32
  const int tid = threadIdx.x;
  const int tx = tid & 15, ty = tid >> 4;
  const int lr = tid >> 1;            // 0..127
  const int lkc = (tid & 1) * 4;      // 0 or 4
  const float* __restrict__ ar = xm + (size_t)(mb * 128 + lr) * C_ + lkc;
  const float* __restrict__ br = Wqkv + (size_t)(nb * 128 + lr) * C_ + lkc;
  float acc[8][8] = {};
  for (int k0 = 0; k0 < C_; k0 += 8) {
    const float4 av = *(const float4*)(ar + k0);
    const float4 bv = *(const float4*)(br + k0);
    __syncthreads();
    As[lkc + 0][lr] = av.x; As[lkc + 1][lr] = av.y;
    As[lkc + 2][lr] = av.z; As[lkc + 3][lr] = av.w;
    Bs[lkc + 0][lr] = bv.x; Bs[lkc + 1][lr] = bv.y;
    Bs[lkc + 2][lr] = bv.z; Bs[lkc + 3][lr] = bv.w;
    __syncthreads();
#pragma unroll
    for (int k = 0; k < 8; k++) {
      float a_[8], b_[8];
      *(float4*)&a_[0] = *(const float4*)&As[k][ty * 8];
      *(float4*)&a_[4] = *(const float4*)&As[k][ty * 8 + 4];
      *(float4*)&b_[0] = *(const float4*)&Bs[k][tx * 8];
      *(float4*)&b_[4] = *(const float4*)&Bs[k][tx * 8 + 4];
#pragma unroll
      for (int i = 0; i < 8; i++)
#pragma unroll
        for (int j = 0; j < 8; j++) acc[i][j] = fmaf(a_[i], b_[j], acc[i][j]);
    }
  }
  const int n0 = nb * 128 + tx * 8;
  const int w = n0 >> 10, h = (n0 >> 6) & 15, dc = n0 & 63;
  const int m0 = mb * 128 + ty * 8;
  const int bb = m0 >> 10, t0 = m0 & 1023;
  if (w < 2) {
    const float sc = (w == 0) ? 0.125f : 1.0f;
    const size_t base = ((size_t)(bb * 3 + w) * 16 + h) * 65536 + (size_t)t0 * 64 + dc;
#pragma unroll
    for (int i = 0; i < 8; i++) {
      unsigned hh[8], ll[8];
#pragma unroll
      for (int j = 0; j < 8; j++) {
        const float f = acc[i][j] * sc;
        const unsigned short hv = f2bf_rtne(f);
        const float fh = __uint_as_float((unsigned)hv << 16);
        const unsigned short lv = f2bf_rtne(f - fh);
        hh[j] = hv; ll[j] = lv;
      }
      *(uint4*)&gh[base + (size_t)i * 64] =
          make_uint4(hh[0] | (hh[1] << 16), hh[2] | (hh[3] << 16),
                     hh[4] | (hh[5] << 16), hh[6] | (hh[7] << 16));
      *(uint4*)&gl[base + (size_t)i * 64] =
          make_uint4(ll[0] | (ll[1] << 16), ll[2] | (ll[3] << 16),
                     ll[4] | (ll[5] << 16), ll[6] | (ll[7] << 16));
    }
  } else {
    const size_t base = ((size_t)(bb * 3 + 2) * 16 + h) * 65536 + t0;
#pragma unroll
    for (int j = 0; j < 8; j++) {
      unsigned hh[8], ll[8];
#pragma unroll
      for (int i = 0; i < 8; i++) {
        const float f = acc[i][j];
        const unsigned short hv = f2bf_rtne(f);
        const float fh = __uint_as_float((unsigned)hv << 16);
        const unsigned short lv = f2bf_rtne(f - fh);
        hh[i] = hv; ll[i] = lv;
      }
      *(uint4*)&gh[base + (size_t)(dc + j) * 1024] =
          make_uint4(hh[0] | (hh[1] << 16), hh[2] | (hh[3] << 16),
                     hh[4] | (hh[5] << 16), hh[6] | (hh[7] << 16));
      *(uint4*)&gl[base + (size_t)(dc + j) * 1024] =
          make_uint4(ll[0] | (ll[1] << 16), ll[2] | (ll[3] << 16),
                     ll[4] | (ll[5] << 16), ll[6] | (ll[7] << 16));
    }
  }
}

// ---------------------------------------------------------------------------
// K11: flash attention via bf16x3 MFMA (hi*hi + hi*lo + lo*hi, err ~2^-17).
// 4 waves; wave w owns q-rows w*16..+15 and all 64 k-cols / d-cols.
// LDS: Qh/Ql [64][64] XOR-swizzled (kb ^= row&7), K(+P alias)/VT [64][72] pad.
// P written fp32 into dead K region, split to bf16 at fragment load.
// m/l/alpha in registers (replicated across 16-lane row groups).
// LDS total 53,248 B -> 3 blocks/CU.
// ---------------------------------------------------------------------------
__global__ __launch_bounds__(256, 3) void k_attn(const unsigned short* __restrict__ gh,
                                                 const unsigned short* __restrict__ gl,
                                                 float* __restrict__ om) {
  __shared__ __align__(16) unsigned short Qh[64][64], Ql[64][64];
  __shared__ __align__(16) unsigned short KP[2][64][72];   // K hi/lo, then P fp32
  __shared__ __align__(16) unsigned short VTh[64][72], VTl[64][72];
  float* const Pf = (float*)&KP[0][0][0];                  // [64][68] fp32 view
  const int qb = blockIdx.x, h = blockIdx.y, bz = blockIdx.z;
  const int tid = threadIdx.x;
  const int lane = tid & 63, wv = tid >> 6;
  const int fr = lane & 15, fg = lane >> 4;
  const int lr = tid >> 2, lc = (tid & 3) * 16;
  const size_t qbase = ((size_t)(bz * 3 + 0) * 16 + h) * 65536;
  const size_t kbase = ((size_t)(bz * 3 + 1) * 16 + h) * 65536;
  const size_t vbase = ((size_t)(bz * 3 + 2) * 16 + h) * 65536;
  { // stage Q (already scaled by 0.125 in k_qkv), XOR-swizzled
    const size_t o0 = qbase + (size_t)(qb * 64 + lr) * 64 + lc;
    const int sw = lr & 7, kb0 = lc >> 3;
    *(uint4*)&Qh[lr][((kb0 + 0) ^ sw) * 8] = *(const uint4*)(gh + o0);
    *(uint4*)&Qh[lr][((kb0 + 1) ^ sw) * 8] = *(const uint4*)(gh + o0 + 8);
    *(uint4*)&Ql[lr][((kb0 + 0) ^ sw) * 8] = *(const uint4*)(gl + o0);
    *(uint4*)&Ql[lr][((kb0 + 1) ^ sw) * 8] = *(const uint4*)(gl + o0 + 8);
  }
  f32x4 o_[4] = {};
  float m_r[4] = {-INFINITY, -INFINITY, -INFINITY, -INFINITY};
  float l_r[4] = {0.0f, 0.0f, 0.0f, 0.0f};
  float alpha[4];
  for (int kt = 0; kt < 16; kt++) {
    __syncthreads();          // prev PV reads of KP(P)/VT done
    { // stage K rows + VT rows (pure coalesced copies, V pre-transposed)
      const size_t ko = kbase + (size_t)(kt * 64 + lr) * 64 + lc;
      *(uint4*)&KP[0][lr][lc]     = *(const uint4*)(gh + ko);
      *(uint4*)&KP[0][lr][lc + 8] = *(const uint4*)(gh + ko + 8);
      *(uint4*)&KP[1][lr][lc]     = *(const uint4*)(gl + ko);
      *(uint4*)&KP[1][lr][lc + 8] = *(const uint4*)(gl + ko + 8);
      const size_t vo = vbase + (size_t)lr * 1024 + kt * 64 + lc;
      *(uint4*)&VTh[lr][lc]     = *(const uint4*)(gh + vo);
      *(uint4*)&VTh[lr][lc + 8] = *(const uint4*)(gh + vo + 8);
      *(uint4*)&VTl[lr][lc]     = *(const uint4*)(gl + vo);
      *(uint4*)&VTl[lr][lc + 8] = *(const uint4*)(gl + vo + 8);
    }
    __syncthreads();          // staging visible
    // QK^T: S[q][k] = Q . K (both row-frags -> D = A*B^T), bf16x3
    f32x4 sacc[4] = {};
#pragma unroll
    for (int ks = 0; ks < 2; ks++) {
      const int kb = ks * 4 + fg;
      const short8v qh_ = *(const short8v*)&Qh[wv * 16 + fr][(kb ^ (fr & 7)) * 8];
      const short8v ql_ = *(const short8v*)&Ql[wv * 16 + fr][(kb ^ (fr & 7)) * 8];
#pragma unroll
      for (int nn = 0; nn < 4; nn++) {
        const short8v kh_ = *(const short8v*)&KP[0][nn * 16 + fr][ks * 32 + fg * 8];
        const short8v kl_ = *(const short8v*)&KP[1][nn * 16 + fr][ks * 32 + fg * 8];
        sacc[nn] = __builtin_amdgcn_mfma_f32_16x16x32_bf16(ql_, kh_, sacc[nn], 0, 0, 0);
        sacc[nn] = __builtin_amdgcn_mfma_f32_16x16x32_bf16(qh_, kl_, sacc[nn], 0, 0, 0);
        sacc[nn] = __builtin_amdgcn_mfma_f32_16x16x32_bf16(qh_, kh_, sacc[nn], 0, 0, 0);
      }
    }
    // online softmax (rows = fg*4 + r, cols spread over 16 lanes x 4 nn)
#pragma unroll
    for (int r = 0; r < 4; r++) {
      float tmax = fmaxf(fmaxf(sacc[0][r], sacc[1][r]), fmaxf(sacc[2][r], sacc[3][r]));
#pragma unroll
      for (int off = 8; off; off >>= 1) tmax = fmaxf(tmax, __shfl_xor(tmax, off, 16));
      const float mn = fmaxf(m_r[r], tmax);
      alpha[r] = expf(m_r[r] - mn);
      float s_ = 0.0f;
#pragma unroll
      for (int nn = 0; nn < 4; nn++) { sacc[nn][r] = expf(sacc[nn][r] - mn); s_ += sacc[nn][r]; }
#pragma unroll
      for (int off = 8; off; off >>= 1) s_ += __shfl_xor(s_, off, 16);
      m_r[r] = mn;
      l_r[r] = l_r[r] * alpha[r] + s_;
    }
    __syncthreads();          // all K-frag reads done -> overwrite region as P
#pragma unroll
    for (int nn = 0; nn < 4; nn++)
#pragma unroll
      for (int r = 0; r < 4; r++)
        Pf[(wv * 16 + fg * 4 + r) * 68 + nn * 16 + fr] = sacc[nn][r];
    __syncthreads();          // P visible (cross-lane)
#pragma unroll
    for (int nd = 0; nd < 4; nd++)
#pragma unroll
      for (int r = 0; r < 4; r++) o_[nd][r] *= alpha[r];
    // PV: O[q][d] = P . V = A(P rows) * B(VT rows)^T, bf16x3
#pragma unroll
    for (int ks = 0; ks < 2; ks++) {
      float pf[8];
      *(float4*)&pf[0] = *(const float4*)&Pf[(wv * 16 + fr) * 68 + ks * 32 + fg * 8];
      *(float4*)&pf[4] = *(const float4*)&Pf[(wv * 16 + fr) * 68 + ks * 32 + fg * 8 + 4];
      short8v ph_, pl_;
      split8(pf, ph_, pl_);
#pragma unroll
      for (int nd = 0; nd < 4; nd++) {
        const short8v vh_ = *(const short8v*)&VTh[nd * 16 + fr][ks * 32 + fg * 8];
        const short8v vl_ = *(const short8v*)&VTl[nd * 16 + fr][ks * 32 + fg * 8];
        o_[nd] = __builtin_amdgcn_mfma_f32_16x16x32_bf16(pl_, vh_, o_[nd], 0, 0, 0);
        o_[nd] = __builtin_amdgcn_mfma_f32_16x16x32_bf16(ph_, vl_, o_[nd], 0, 0, 0);
        o_[nd] = __builtin_amdgcn_mfma_f32_16x16x32_bf16(ph_, vh_, o_[nd], 0, 0, 0);
      }
    }
  }
  // epilogue: D layout col = lane&15 (d in 16-block), row = fg*4 + r (q)
#pragma unroll
  for (int r = 0; r < 4; r++) {
    const float inv = 1.0f / l_r[r];
    const int t = qb * 64 + wv * 16 + fg * 4 + r;
#pragma unroll
    for (int nd = 0; nd < 4; nd++)
      om[((size_t)bz * ND_ + t) * C_ + h * 64 + nd * 16 + fr] = o_[nd][r] * inv;
  }
}

// ---------------------------------------------------------------------------
// K12: proj GEMM, 128x128 tile, 8x8 per thread, BK=8. ym = om@Wp^T + bp
// ---------------------------------------------------------------------------
__global__ __launch_bounds__(256) void k_proj(const float* __restrict__ om,
                                              const float* __restrict__ Wp,
                                              const float* __restrict__ bp,
                                              float* __restrict__ ym) {
  __shared__ __align__(16) float As[8][132];
  __shared__ __align__(16) float Bs[8][132];
  const int nb = blockIdx.x;   // 8
  const int mb = blockIdx.y;   // 32
  const int tid = threadIdx.x;
  const int tx = tid & 15, ty = tid >> 4;
  const int lr = tid >> 1;
  const int lkc = (tid & 1) * 4;
  const float* __restrict__ ar = om + (size_t)(mb * 128 + lr) * C_ + lkc;
  const float* __restrict__ br = Wp + (size_t)(nb * 128 + lr) * C_ + lkc;
  float acc[8][8] = {};
  for (int k0 = 0; k0 < C_; k0 += 8) {
    const float4 av = *(const float4*)(ar + k0);
    const float4 bv = *(const float4*)(br + k0);
    __syncthreads();
    As[lkc + 0][lr] = av.x; As[lkc + 1][lr] = av.y;
    As[lkc + 2][lr] = av.z; As[lkc + 3][lr] = av.w;
    Bs[lkc + 0][lr] = bv.x; Bs[lkc + 1][lr] = bv.y;
    Bs[lkc + 2][lr] = bv.z; Bs[lkc + 3][lr] = bv.w;
    __syncthreads();
#pragma unroll
    for (int k = 0; k < 8; k++) {
      float a_[8], b_[8];
      *(float4*)&a_[0] = *(const float4*)&As[k][ty * 8];
      *(float4*)&a_[4] = *(const float4*)&As[k][ty * 8 + 4];
      *(float4*)&b_[0] = *(const float4*)&Bs[k][tx * 8];
      *(float4*)&b_[4] = *(const float4*)&Bs[k][tx * 8 + 4];
#pragma unroll
      for (int i = 0; i < 8; i++)
#pragma unroll
        for (int j = 0; j < 8; j++) acc[i][j] = fmaf(a_[i], b_[j], acc[i][j]);
    }
  }
  const int n0 = nb * 128 + tx * 8;
  const float4 b0 = *(const float4*)(bp + n0);
  const float4 b1 = *(const float4*)(bp + n0 + 4);
#pragma unroll
  for (int i = 0; i < 8; i++) {
    const int m = mb * 128 + ty * 8 + i;
    float* dst = ym + (size_t)m * C_ + n0;
    *(float4*)dst       = make_float4(acc[i][0] + b0.x, acc[i][1] + b0.y,
                                      acc[i][2] + b0.z, acc[i][3] + b0.w);
    *(float4*)(dst + 4) = make_float4(acc[i][4] + b1.x, acc[i][5] + b1.y,
                                      acc[i][6] + b1.z, acc[i][7] + b1.w);
  }
}

// K13: scatter merged rows back to all 4096 tokens
__global__ __launch_bounds__(256) void k_unmerge(const float* __restrict__ ym,
                                                 const int* __restrict__ rowmap,
                                                 float* __restrict__ out) {
  const int blk = blockIdx.x;                 // B_*N_
  const int bz = blk >> 12;
  const int r = rowmap[blk];
  const float4* src = (const float4*)(ym + ((size_t)bz * ND_ + r) * C_);
  float4* dst = (float4*)(out + (size_t)blk * C_);
  dst[threadIdx.x] = src[threadIdx.x];
}

// ---------------------------------------------------------------------------
extern "C" void kernel_launch(void* const* d_in, const int* in_sizes, int n_in,
                              void* d_out, int out_size, void* d_ws, size_t ws_size,
                              hipStream_t stream) {
  const float* x    = (const float*)d_in[0];
  const float* Wqkv = (const float*)d_in[1];
  const float* Wp   = (const float*)d_in[2];
  const float* bp   = (const float*)d_in[3];
  char* ws = (char*)d_ws;
  double* dinv    = (double*)(ws + 0);          //  131072 B
  int*   b_idx    = (int*)(ws + 131072);        //    4096 B
  int*   a_idx    = (int*)(ws + 135168);        //   12288 B
  int*   node_idx = (int*)(ws + 147456);        //   49152 B
  int*   cnt      = (int*)(ws + 196608);        //   16384 B
  int*   rowmap   = (int*)(ws + 212992);        //   65536 B
  int*   flagr    = (int*)(ws + 278528);        //   49152 B
  float* pv1      = (float*)(ws + 327680);      //  786432 B
  int*   pi1      = (int*)(ws + 1114112);       //  786432 B
  float* pv2      = (float*)(ws + 1900544);     //  786432 B
  int*   pi2      = (int*)(ws + 2686976);       //  786432 B
  // xh/xl live k_prep..k_scores; region later overwritten by xm + gh/gl.
  unsigned short* xh = (unsigned short*)(ws + 3473408);    // 33,554,432 B
  unsigned short* xl = (unsigned short*)(ws + 37027840);   // 33,554,432 B
  float* xm       = (float*)(ws + 3473408);    // 16.78 MB (aliases xh)
  // gh/gl: bf16 hi/lo qkv (Q scaled, V transposed). 25.17 MB each.
  unsigned short* gh = (unsigned short*)(ws + 20250624);
  unsigned short* gl = (unsigned short*)(ws + 45416448);   // ends 70,582,272
  float* om       = (float*)(ws + 70582272);   // 16.78 MB
  float* ym       = xm;                        // reuse (xm consumed by k_qkv)
  float* out      = (float*)d_out;

  hipMemsetAsync(cnt, 0, B_ * ND_ * sizeof(int), stream);
  k_init_indices<<<1, 1024, 0, stream>>>(b_idx, a_idx);
  k_row_norms<<<B_ * N_, 256, 0, stream>>>(x, dinv);
  k_prep<<<B_ * N_, 256, 0, stream>>>(x, dinv, xh, xl);
  k_scores_mfma<<<dim3(16, 48, B_), 256, 0, stream>>>(xh, xl, a_idx, b_idx, pv1, pi1, pv2, pi2);
  k_finalize<<<(B_ * NA_) / 256, 256, 0, stream>>>(pv1, pi1, pv2, pi2, node_idx, flagr);
  k_recheck<<<B_ * NA_, 256, 0, stream>>>(x, dinv, a_idx, b_idx, pv1, pi1, pv2, pi2, flagr, node_idx);
  k_counts_rowmap<<<(B_ * N_) / 256, 256, 0, stream>>>(a_idx, b_idx, node_idx, cnt, rowmap);
  k_merge_init<<<B_ * ND_, 256, 0, stream>>>(x, b_idx, xm);
  k_merge_add<<<B_ * NA_, 256, 0, stream>>>(x, a_idx, node_idx, xm);
  k_merge_scale<<<B_ * ND_, 256, 0, stream>>>(xm, cnt);
  k_qkv<<<dim3(24, 32), 256, 0, stream>>>(xm, Wqkv, gh, gl);
  k_attn<<<dim3(16, 16, B_), 256, 0, stream>>>(gh, gl, om);
  k_proj<<<dim3(8, 32), 256, 0, stream>>>(om, Wp, bp, ym);
  k_unmerge<<<B_ * N_, 256, 0, stream>>>(ym, rowmap, out);
}

// Round 5
// 942.392 us; speedup vs baseline: 1.7898x; 1.3606x over previous
//
#include <hip/hip_runtime.h>
#include <cmath>

// Problem constants (B,N,DIM,HEADS)=(4,4096,1024,16), SX=SY=2, ratio .9
#define B_  4
#define N_  4096
#define C_  1024
#define H_  16
#define D_  64
#define ND_ 1024   // num dst tokens (one per 2x2 block)
#define NA_ 3072   // num src (a) tokens
// r = min(3072, int(4096*0.9)) = 3072  => unm empty, sort permutation cancels.

typedef __attribute__((ext_vector_type(8))) short short8v;
typedef __attribute__((ext_vector_type(4))) float f32x4;

// ---------------------------------------------------------------------------
// threefry2x32 (20 rounds), returns BOTH output words.
// ---------------------------------------------------------------------------
__device__ inline void tf2x32(unsigned k0, unsigned k1, unsigned x0, unsigned x1,
                              unsigned& o0, unsigned& o1) {
  const unsigned ks2 = 0x1BD11BDAu ^ k0 ^ k1;
  x0 += k0; x1 += k1;
#define RND_(r) { x0 += x1; x1 = (x1 << (r)) | (x1 >> (32 - (r))); x1 ^= x0; }
  RND_(13) RND_(15) RND_(26) RND_(6)
  x0 += k1;  x1 += ks2 + 1u;
  RND_(17) RND_(29) RND_(16) RND_(24)
  x0 += ks2; x1 += k0 + 2u;
  RND_(13) RND_(15) RND_(26) RND_(6)
  x0 += k0;  x1 += k1 + 3u;
  RND_(17) RND_(29) RND_(16) RND_(24)
  x0 += k1;  x1 += ks2 + 4u;
  RND_(13) RND_(15) RND_(26) RND_(6)
  x0 += ks2; x1 += k0 + 5u;
#undef RND_
  o0 = x0; o1 = x1;
}

// ---------------------------------------------------------------------------
// K1 (VERIFIED r7): jax.random.randint(key(33),(32,32),0,4)
// ---------------------------------------------------------------------------
__global__ __launch_bounds__(1024) void k_init_indices(int* __restrict__ b_idx,
                                                       int* __restrict__ a_idx) {
  __shared__ unsigned char randk[1024];
  __shared__ int wtot[16], wpre[16];
  const int tid = threadIdx.x;
  {
    unsigned c0, c1;
    tf2x32(0u, 33u, 0u, 1u, c0, c1);                 // k2 = split(key)[1]
    unsigned d0, d1;
    tf2x32(c0, c1, 0u, (unsigned)tid, d0, d1);       // random_bits element p
    randk[tid] = (unsigned char)((d0 ^ d1) & 3u);    // xor-fold, % span
  }
  __syncthreads();
  const int base_t = tid * 4;
  int f[4]; int cnt = 0;
#pragma unroll
  for (int j = 0; j < 4; j++) {
    const int t = base_t + j;
    const int y = t >> 6, xc = t & 63;
    const int bi = (y >> 1) * 32 + (xc >> 1);
    const int k  = (y & 1) * 2 + (xc & 1);
    f[j] = (randk[bi] == (unsigned char)k) ? 1 : 0;
    cnt += f[j];
  }
  const int lane = tid & 63, wave = tid >> 6;
  int incl = cnt;
#pragma unroll
  for (int off = 1; off < 64; off <<= 1) {
    int nb = __shfl_up(incl, off, 64);
    if (lane >= off) incl += nb;
  }
  if (lane == 63) wtot[wave] = incl;
  __syncthreads();
  if (tid == 0) { int s = 0; for (int w = 0; w < 16; w++) { wpre[w] = s; s += wtot[w]; } }
  __syncthreads();
  int P = wpre[wave] + (incl - cnt);   // #dst strictly before base_t
#pragma unroll
  for (int j = 0; j < 4; j++) {
    const int t = base_t + j;
    if (f[j]) { b_idx[P] = t; P++; }
    else      { a_idx[t - P] = t; }
  }
}

// ---------------------------------------------------------------------------
// K2: per-token inverse L2 norm of x, fp64
// ---------------------------------------------------------------------------
__global__ __launch_bounds__(256) void k_row_norms(const float* __restrict__ x,
                                                   double* __restrict__ dinv) {
  const int row = blockIdx.x;                 // B_*N_
  const float* xr = x + (size_t)row * C_;
  const int tid = threadIdx.x;
  float4 v = ((const float4*)xr)[tid];
  double s = (double)v.x * (double)v.x + (double)v.y * (double)v.y +
             (double)v.z * (double)v.z + (double)v.w * (double)v.w;
#pragma unroll
  for (int off = 32; off; off >>= 1) s += __shfl_down(s, off, 64);
  __shared__ double wsum[4];
  if ((tid & 63) == 0) wsum[tid >> 6] = s;
  __syncthreads();
  if (tid == 0) {
    double t = wsum[0] + wsum[1] + wsum[2] + wsum[3];
    dinv[row] = 1.0 / sqrt(t);
  }
}

// ---------------------------------------------------------------------------
// bf16 split helpers (RTNE)
// ---------------------------------------------------------------------------
__device__ inline unsigned short f2bf_rtne(float f) {
  const unsigned u = __float_as_uint(f);
  return (unsigned short)((u + 0x7FFFu + ((u >> 16) & 1u)) >> 16);
}

__device__ inline void split8(const float* f, short8v& h8, short8v& l8) {
#pragma unroll
  for (int j = 0; j < 8; j++) {
    const unsigned short hv = f2bf_rtne(f[j]);
    const float fh = __uint_as_float((unsigned)hv << 16);
    const unsigned short lv = f2bf_rtne(f[j] - fh);
    h8[j] = (short)hv; l8[j] = (short)lv;
  }
}

// ---------------------------------------------------------------------------
// K2b: normalized rows split into bf16 hi + bf16 lo (RTNE), for MFMA scores.
// ---------------------------------------------------------------------------
__global__ __launch_bounds__(256) void k_prep(const float* __restrict__ x,
                                              const double* __restrict__ dinv,
                                              unsigned short* __restrict__ xh,
                                              unsigned short* __restrict__ xl) {
  const int row = blockIdx.x;                 // B_*N_
  const float ia = (float)dinv[row];
  const float4 v = ((const float4*)(x + (size_t)row * C_))[threadIdx.x];
  float f[4] = {v.x * ia, v.y * ia, v.z * ia, v.w * ia};
  unsigned h[4], l[4];
#pragma unroll
  for (int j = 0; j < 4; j++) {
    h[j] = f2bf_rtne(f[j]);
    const float fh = __uint_as_float(h[j] << 16);
    l[j] = f2bf_rtne(f[j] - fh);
  }
  const size_t o = (size_t)row * C_ + threadIdx.x * 4;
  uint2 ph, pl;
  ph.x = h[0] | (h[1] << 16); ph.y = h[2] | (h[3] << 16);
  pl.x = l[0] | (l[1] << 16); pl.y = l[2] | (l[3] << 16);
  *(uint2*)&xh[o] = ph;
  *(uint2*)&xl[o] = pl;
}

// ---------------------------------------------------------------------------
// K2c: split Wqkv (3072x1024) and Wp (1024x1024) into bf16 hi/lo.
// Runs after k_scores_mfma (regions alias dead xl).
// ---------------------------------------------------------------------------
__global__ __launch_bounds__(256) void k_prep_w(const float* __restrict__ Wqkv,
                                                const float* __restrict__ Wp,
                                                unsigned short* __restrict__ wqh,
                                                unsigned short* __restrict__ wql,
                                                unsigned short* __restrict__ wph,
                                                unsigned short* __restrict__ wpl) {
  const int row = blockIdx.x;            // 0..4095
  const float* src;
  unsigned short *dh, *dl;
  size_t o;
  if (row < 3072) { src = Wqkv + (size_t)row * C_; dh = wqh; dl = wql; o = (size_t)row * C_; }
  else { src = Wp + (size_t)(row - 3072) * C_; dh = wph; dl = wpl; o = (size_t)(row - 3072) * C_; }
  const float4 v = ((const float4*)src)[threadIdx.x];
  const float f[4] = {v.x, v.y, v.z, v.w};
  unsigned h4[4], l4[4];
#pragma unroll
  for (int j = 0; j < 4; j++) {
    h4[j] = f2bf_rtne(f[j]);
    const float fh = __uint_as_float(h4[j] << 16);
    l4[j] = f2bf_rtne(f[j] - fh);
  }
  uint2 ph, pl;
  ph.x = h4[0] | (h4[1] << 16); ph.y = h4[2] | (h4[3] << 16);
  pl.x = l4[0] | (l4[1] << 16); pl.y = l4[2] | (l4[3] << 16);
  *(uint2*)&dh[o + threadIdx.x * 4] = ph;
  *(uint2*)&dl[o + threadIdx.x * 4] = pl;
}

// top-2 merge tracking both indices
__device__ inline void top2m(float& v1, int& i1, float& v2, int& i2,
                             float ov1, int oi1, float ov2, int oi2) {
  if (ov1 > v1 || (ov1 == v1 && oi1 < i1)) {
    if (v1 > ov2 || (v1 == ov2 && i1 < oi2)) { v2 = v1; i2 = i1; }
    else { v2 = ov2; i2 = oi2; }
    v1 = ov1; i1 = oi1;
  } else if (ov1 > v2 || (ov1 == v2 && oi1 < i2)) {
    v2 = ov1; i2 = oi1;
  }
}

// ---------------------------------------------------------------------------
// K3: scores via bf16x3 MFMA (verified R2). 64x64 tile, top-2 epilogue.
// ---------------------------------------------------------------------------
__global__ __launch_bounds__(256) void k_scores_mfma(
    const unsigned short* __restrict__ xh, const unsigned short* __restrict__ xl,
    const int* __restrict__ a_idx, const int* __restrict__ b_idx,
    float* __restrict__ pv1, int* __restrict__ pi1,
    float* __restrict__ pv2, int* __restrict__ pi2) {
  __shared__ unsigned short Ah[64][40], Al[64][40], Bh[64][40], Bl[64][40];
  __shared__ float mv1[64][2], mv2[64][2];
  __shared__ int   mi1[64][2], mi2[64][2];
  const int bz = blockIdx.z, cb = blockIdx.x, sb = blockIdx.y;
  const int tid = threadIdx.x;
  const int srow = tid >> 2, sq = tid & 3;       // staging row / 16B chunk
  const int ga = a_idx[sb * 64 + srow];
  const int gb = b_idx[cb * 64 + srow];
  const size_t abase = ((size_t)bz * N_ + ga) * C_;
  const size_t bbase = ((size_t)bz * N_ + gb) * C_;
  const int wv = tid >> 6, lane = tid & 63;
  const int wr = wv >> 1, wc = wv & 1;
  const int fr = lane & 15, fg = lane >> 4;      // frag row-in-16 / k-group
  f32x4 acc[2][2] = {};
  for (int k0 = 0; k0 < C_; k0 += 32) {
    __syncthreads();
    *(uint4*)&Ah[srow][sq * 8] = *(const uint4*)(xh + abase + k0 + sq * 8);
    *(uint4*)&Al[srow][sq * 8] = *(const uint4*)(xl + abase + k0 + sq * 8);
    *(uint4*)&Bh[srow][sq * 8] = *(const uint4*)(xh + bbase + k0 + sq * 8);
    *(uint4*)&Bl[srow][sq * 8] = *(const uint4*)(xl + bbase + k0 + sq * 8);
    __syncthreads();
    short8v ah[2], al[2], bh[2], bl[2];
#pragma unroll
    for (int i = 0; i < 2; i++) {
      const int ra = wr * 32 + i * 16 + fr;
      const int rb = wc * 32 + i * 16 + fr;
      ah[i] = *(const short8v*)&Ah[ra][fg * 8];
      al[i] = *(const short8v*)&Al[ra][fg * 8];
      bh[i] = *(const short8v*)&Bh[rb][fg * 8];
      bl[i] = *(const short8v*)&Bl[rb][fg * 8];
    }
#pragma unroll
    for (int i = 0; i < 2; i++)
#pragma unroll
      for (int j = 0; j < 2; j++) {
        acc[i][j] = __builtin_amdgcn_mfma_f32_16x16x32_bf16(al[i], bh[j], acc[i][j], 0, 0, 0);
        acc[i][j] = __builtin_amdgcn_mfma_f32_16x16x32_bf16(ah[i], bl[j], acc[i][j], 0, 0, 0);
        acc[i][j] = __builtin_amdgcn_mfma_f32_16x16x32_bf16(ah[i], bh[j], acc[i][j], 0, 0, 0);
      }
  }
  // top-2 epilogue. D layout: col = lane&15, row = (lane>>4)*4 + reg (m89).
#pragma unroll
  for (int i = 0; i < 2; i++) {
#pragma unroll
    for (int r = 0; r < 4; r++) {
      const float va = acc[i][0][r]; const int ca = cb * 64 + wc * 32 + fr;
      const float vb = acc[i][1][r]; const int cbg = ca + 16;
      float v1, v2; int i1, i2;
      if (vb > va) { v1 = vb; i1 = cbg; v2 = va; i2 = ca; }
      else         { v1 = va; i1 = ca;  v2 = vb; i2 = cbg; }
#pragma unroll
      for (int off = 8; off; off >>= 1) {
        const float ov1 = __shfl_xor(v1, off, 16);
        const int   oi1 = __shfl_xor(i1, off, 16);
        const float ov2 = __shfl_xor(v2, off, 16);
        const int   oi2 = __shfl_xor(i2, off, 16);
        top2m(v1, i1, v2, i2, ov1, oi1, ov2, oi2);
      }
      if (fr == 0) {
        const int rl = wr * 32 + i * 16 + fg * 4 + r;
        mv1[rl][wc] = v1; mi1[rl][wc] = i1; mv2[rl][wc] = v2; mi2[rl][wc] = i2;
      }
    }
  }
  __syncthreads();
  if (tid < 64) {
    float v1 = mv1[tid][0], v2 = mv2[tid][0];
    int   i1 = mi1[tid][0], i2 = mi2[tid][0];
    top2m(v1, i1, v2, i2, mv1[tid][1], mi1[tid][1], mv2[tid][1], mi2[tid][1]);
    const int s = sb * 64 + tid;
    const size_t o = ((size_t)bz * NA_ + s) * 16 + cb;
    pv1[o] = v1; pi1[o] = i1; pv2[o] = v2; pi2[o] = i2;
  }
}

// K4: merge 16 per-tile partials -> node_idx + near-tie flag
__global__ __launch_bounds__(256) void k_finalize(
    const float* __restrict__ pv1, const int* __restrict__ pi1,
    const float* __restrict__ pv2, const int* __restrict__ pi2,
    int* __restrict__ node_idx, int* __restrict__ flagr) {
  const int r = blockIdx.x * 256 + threadIdx.x;   // [0, B_*NA_)
  if (r >= B_ * NA_) return;
  size_t o = (size_t)r * 16;
  float v1 = pv1[o]; int i1 = pi1[o]; float v2 = pv2[o]; int i2 = pi2[o];
  for (int cb = 1; cb < 16; cb++)
    top2m(v1, i1, v2, i2, pv1[o + cb], pi1[o + cb], pv2[o + cb], pi2[o + cb]);
  node_idx[r] = i1;
  flagr[r] = (v1 - v2 < 1e-3f) ? 1 : 0;  // unflagged => true gap > 9e-4 => exact
}

// ---------------------------------------------------------------------------
// K5: candidate-based fp64 recheck for flagged rows.
// ---------------------------------------------------------------------------
__global__ __launch_bounds__(256) void k_recheck(
    const float* __restrict__ x, const double* __restrict__ dinv,
    const int* __restrict__ a_idx, const int* __restrict__ b_idx,
    const float* __restrict__ pv1, const int* __restrict__ pi1,
    const float* __restrict__ pv2, const int* __restrict__ pi2,
    const int* __restrict__ flagr, int* __restrict__ node_idx) {
  const int r = blockIdx.x;                 // bz*NA_ + s
  if (!flagr[r]) return;
  const int bz = r / NA_, s = r % NA_;
  __shared__ double arow[C_];
  __shared__ int cand[1088];
  __shared__ int ncand;
  __shared__ float v1s[16];
  const int tid = threadIdx.x;
  const int ga = a_idx[s];
  const double ia = dinv[bz * N_ + ga];
  const float* xa = x + ((size_t)bz * N_ + ga) * C_;
  for (int c = tid; c < C_; c += 256) arow[c] = (double)xa[c] * ia;
  const size_t o = (size_t)r * 16;
  if (tid < 16) v1s[tid] = pv1[o + tid];
  if (tid == 0) ncand = 0;
  __syncthreads();
  float v1g = v1s[0];
#pragma unroll
  for (int cb = 1; cb < 16; cb++) v1g = fmaxf(v1g, v1s[cb]);
  if (tid < 16) {
    const float tv1 = pv1[o + tid], tv2 = pv2[o + tid];
    if (tv2 >= v1g - 2.5e-4f) {
      const int base = atomicAdd(&ncand, 64);
      for (int j = 0; j < 64; j++) cand[base + j] = tid * 64 + j;
    } else {
      if (tv1 >= v1g - 1e-3f) { cand[atomicAdd(&ncand, 1)] = pi1[o + tid]; }
      if (tv2 >= v1g - 1e-3f) { cand[atomicAdd(&ncand, 1)] = pi2[o + tid]; }
    }
  }
  __syncthreads();
  const int nc = ncand;
  const int lane = tid & 63, wave = tid >> 6;
  double bv = -1e300; int bi = 1 << 30;
  for (int ci = wave; ci < nc; ci += 4) {
    const int d = cand[ci];
    const int gb = b_idx[d];
    const double ib = dinv[bz * N_ + gb];
    const float* xb = x + ((size_t)bz * N_ + gb) * C_;
    double sum = 0.0;
    for (int c = lane; c < C_; c += 64) sum += arow[c] * ((double)xb[c] * ib);
#pragma unroll
    for (int off = 32; off; off >>= 1) sum += __shfl_xor(sum, off, 64);
    if (sum > bv || (sum == bv && d < bi)) { bv = sum; bi = d; }
  }
  __shared__ double bvs[4]; __shared__ int bis[4];
  if (lane == 0) { bvs[wave] = bv; bis[wave] = bi; }
  __syncthreads();
  if (tid == 0) {
    for (int w = 1; w < 4; w++)
      if (bvs[w] > bv || (bvs[w] == bv && bis[w] < bi)) { bv = bvs[w]; bi = bis[w]; }
    node_idx[r] = bi;
  }
}

// K6: counts per dst + token->merged-row map
__global__ __launch_bounds__(256) void k_counts_rowmap(
    const int* __restrict__ a_idx, const int* __restrict__ b_idx,
    const int* __restrict__ node_idx, int* __restrict__ cnt,
    int* __restrict__ rowmap) {
  const int i = blockIdx.x * 256 + threadIdx.x;   // [0, B_*N_)
  if (i >= B_ * N_) return;
  const int bz = i >> 12, j = i & 4095;
  if (j < NA_) {
    const int nd = node_idx[bz * NA_ + j];
    atomicAdd(&cnt[bz * ND_ + nd], 1);
    rowmap[bz * N_ + a_idx[j]] = nd;
  } else {
    const int d = j - NA_;
    rowmap[bz * N_ + b_idx[d]] = d;
  }
}

// K7/K8: merge x into xm (fp32)
__global__ __launch_bounds__(256) void k_merge_init(const float* __restrict__ x,
                                                    const int* __restrict__ b_idx,
                                                    float* __restrict__ xm) {
  const int blk = blockIdx.x;                 // B_*ND_
  const int bz = blk >> 10, d = blk & 1023;
  const float4* src = (const float4*)(x + ((size_t)bz * N_ + b_idx[d]) * C_);
  float4* dst = (float4*)(xm + ((size_t)bz * ND_ + d) * C_);
  dst[threadIdx.x] = src[threadIdx.x];
}

__global__ __launch_bounds__(256) void k_merge_add(const float* __restrict__ x,
                                                   const int* __restrict__ a_idx,
                                                   const int* __restrict__ node_idx,
                                                   float* __restrict__ xm) {
  const int blk = blockIdx.x;                 // B_*NA_ = bz*NA_+i
  const int bz = blk / NA_, i = blk % NA_;
  const int nd = node_idx[blk];
  const float* src = x + ((size_t)bz * N_ + a_idx[i]) * C_;
  float* dst = xm + ((size_t)bz * ND_ + nd) * C_;
  const int c0 = threadIdx.x * 4;
  const float4 v = *(const float4*)(src + c0);
  atomicAdd(&dst[c0 + 0], v.x);
  atomicAdd(&dst[c0 + 1], v.y);
  atomicAdd(&dst[c0 + 2], v.z);
  atomicAdd(&dst[c0 + 3], v.w);
}

// K9: scale merged rows and emit bf16 hi/lo directly (consumed by k_qkv_mfma)
__global__ __launch_bounds__(256) void k_merge_scale(const float* __restrict__ xm,
                                                     const int* __restrict__ cnt,
                                                     unsigned short* __restrict__ xmh,
                                                     unsigned short* __restrict__ xml) {
  const int blk = blockIdx.x;                 // B_*ND_
  const float s = 1.0f + (float)cnt[blk];
  const float4 v = ((const float4*)(xm + (size_t)blk * C_))[threadIdx.x];
  const float f[4] = {v.x / s, v.y / s, v.z / s, v.w / s};
  unsigned h4[4], l4[4];
#pragma unroll
  for (int j = 0; j < 4; j++) {
    h4[j] = f2bf_rtne(f[j]);
    const float fh = __uint_as_float(h4[j] << 16);
    l4[j] = f2bf_rtne(f[j] - fh);
  }
  uint2 ph, pl;
  ph.x = h4[0] | (h4[1] << 16); ph.y = h4[2] | (h4[3] << 16);
  pl.x = l4[0] | (l4[1] << 16); pl.y = l4[2] | (l4[3] << 16);
  const size_t o = (size_t)blk * C_ + threadIdx.x * 4;
  *(uint2*)&xmh[o] = ph;
  *(uint2*)&xml[o] = pl;
}

// ---------------------------------------------------------------------------
// K10: qkv GEMM via bf16x3 MFMA. M=4096, N=3072, K=1024.
// 128x128 tile, 4 waves (2x2 of 64x64), BK=32, acc 4x4 of 16x16 frags.
// Epilogue writes Q(x0.125)/K [b,h,t,d] and V transposed [b,h,d,t], all hi/lo.
// ---------------------------------------------------------------------------
__global__ __launch_bounds__(256) void k_qkv_mfma(
    const unsigned short* __restrict__ xmh, const unsigned short* __restrict__ xml,
    const unsigned short* __restrict__ wqh, const unsigned short* __restrict__ wql,
    unsigned short* __restrict__ gqh, unsigned short* __restrict__ gql,
    unsigned short* __restrict__ gkh, unsigned short* __restrict__ gkl,
    unsigned short* __restrict__ gvh, unsigned short* __restrict__ gvl) {
  __shared__ __align__(16) unsigned short Ahs[128][40], Als[128][40];
  __shared__ __align__(16) unsigned short Bhs[128][40], Bls[128][40];
  const int nb = blockIdx.x;   // 24
  const int mb = blockIdx.y;   // 32
  const int tid = threadIdx.x;
  const int lane = tid & 63, wv = tid >> 6;
  const int wr = wv >> 1, wc = wv & 1;
  const int fr = lane & 15, fg = lane >> 4;
  const int srow = tid >> 1, scol = (tid & 1) * 16;
  const size_t abase = (size_t)(mb * 128 + srow) * C_ + scol;
  const size_t bbase = (size_t)(nb * 128 + srow) * C_ + scol;
  f32x4 acc[4][4] = {};
  for (int k0 = 0; k0 < C_; k0 += 32) {
    __syncthreads();
    *(uint4*)&Ahs[srow][scol]     = *(const uint4*)(xmh + abase + k0);
    *(uint4*)&Ahs[srow][scol + 8] = *(const uint4*)(xmh + abase + k0 + 8);
    *(uint4*)&Als[srow][scol]     = *(const uint4*)(xml + abase + k0);
    *(uint4*)&Als[srow][scol + 8] = *(const uint4*)(xml + abase + k0 + 8);
    *(uint4*)&Bhs[srow][scol]     = *(const uint4*)(wqh + bbase + k0);
    *(uint4*)&Bhs[srow][scol + 8] = *(const uint4*)(wqh + bbase + k0 + 8);
    *(uint4*)&Bls[srow][scol]     = *(const uint4*)(wql + bbase + k0);
    *(uint4*)&Bls[srow][scol + 8] = *(const uint4*)(wql + bbase + k0 + 8);
    __syncthreads();
    short8v bh[4], bl[4];
#pragma unroll
    for (int j = 0; j < 4; j++) {
      bh[j] = *(const short8v*)&Bhs[wc * 64 + j * 16 + fr][fg * 8];
      bl[j] = *(const short8v*)&Bls[wc * 64 + j * 16 + fr][fg * 8];
    }
#pragma unroll
    for (int i = 0; i < 4; i++) {
      const short8v ah = *(const short8v*)&Ahs[wr * 64 + i * 16 + fr][fg * 8];
      const short8v al = *(const short8v*)&Als[wr * 64 + i * 16 + fr][fg * 8];
#pragma unroll
      for (int j = 0; j < 4; j++) {
        acc[i][j] = __builtin_amdgcn_mfma_f32_16x16x32_bf16(al, bh[j], acc[i][j], 0, 0, 0);
        acc[i][j] = __builtin_amdgcn_mfma_f32_16x16x32_bf16(ah, bl[j], acc[i][j], 0, 0, 0);
        acc[i][j] = __builtin_amdgcn_mfma_f32_16x16x32_bf16(ah, bh[j], acc[i][j], 0, 0, 0);
      }
    }
  }
  // D layout: col(n within 16) = fr, row(m within 16) = fg*4 + r.
  const int nq = nb * 2 + wc;          // n>>6: 0..47
  const int w = nq >> 4, h = nq & 15;  // tensor / head
  const int bb = mb >> 3;              // batch
  const int tb = (mb & 7) * 128 + wr * 64;
  const size_t base = (size_t)(bb * 16 + h) * 65536;
  if (w < 2) {
    unsigned short* __restrict__ dh = (w == 0) ? gqh : gkh;
    unsigned short* __restrict__ dl = (w == 0) ? gql : gkl;
    const float sc = (w == 0) ? 0.125f : 1.0f;
#pragma unroll
    for (int i = 0; i < 4; i++)
#pragma unroll
      for (int j = 0; j < 4; j++) {
        const int dc = j * 16 + fr;
#pragma unroll
        for (int r = 0; r < 4; r++) {
          const int t = tb + i * 16 + fg * 4 + r;
          const float f = acc[i][j][r] * sc;
          const unsigned short hv = f2bf_rtne(f);
          const float fh = __uint_as_float((unsigned)hv << 16);
          const unsigned short lv = f2bf_rtne(f - fh);
          dh[base + (size_t)t * 64 + dc] = hv;
          dl[base + (size_t)t * 64 + dc] = lv;
        }
      }
  } else {
#pragma unroll
    for (int i = 0; i < 4; i++)
#pragma unroll
      for (int j = 0; j < 4; j++) {
        const int dc = j * 16 + fr;
        const int t0 = tb + i * 16 + fg * 4;
        unsigned hv[4], lv[4];
#pragma unroll
        for (int r = 0; r < 4; r++) {
          const float f = acc[i][j][r];
          hv[r] = f2bf_rtne(f);
          const float fh = __uint_as_float(hv[r] << 16);
          lv[r] = f2bf_rtne(f - fh);
        }
        uint2 ph, pl;
        ph.x = hv[0] | (hv[1] << 16); ph.y = hv[2] | (hv[3] << 16);
        pl.x = lv[0] | (lv[1] << 16); pl.y = lv[2] | (lv[3] << 16);
        *(uint2*)&gvh[base + (size_t)dc * 1024 + t0] = ph;
        *(uint2*)&gvl[base + (size_t)dc * 1024 + t0] = pl;
      }
  }
}

// ---------------------------------------------------------------------------
// K11: flash attention via bf16x3 MFMA (verified R4). Inputs now separate
// Q/K/V hi-lo arrays; epilogue writes om as bf16 hi/lo for MFMA proj.
// ---------------------------------------------------------------------------
__global__ __launch_bounds__(256, 3) void k_attn(
    const unsigned short* __restrict__ gqh, const unsigned short* __restrict__ gql,
    const unsigned short* __restrict__ gkh, const unsigned short* __restrict__ gkl,
    const unsigned short* __restrict__ gvh, const unsigned short* __restrict__ gvl,
    unsigned short* __restrict__ omh, unsigned short* __restrict__ oml) {
  __shared__ __align__(16) unsigned short Qh[64][64], Ql[64][64];
  __shared__ __align__(16) unsigned short KP[2][64][72];   // K hi/lo, then P fp32
  __shared__ __align__(16) unsigned short VTh[64][72], VTl[64][72];
  float* const Pf = (float*)&KP[0][0][0];                  // [64][68] fp32 view
  const int qb = blockIdx.x, h = blockIdx.y, bz = blockIdx.z;
  const int tid = threadIdx.x;
  const int lane = tid & 63, wv = tid >> 6;
  const int fr = lane & 15, fg = lane >> 4;
  const int lr = tid >> 2, lc = (tid & 3) * 16;
  const size_t hb = (size_t)(bz * 16 + h) * 65536;
  { // stage Q (already scaled by 0.125 in k_qkv), XOR-swizzled
    const size_t o0 = hb + (size_t)(qb * 64 + lr) * 64 + lc;
    const int sw = lr & 7, kb0 = lc >> 3;
    *(uint4*)&Qh[lr][((kb0 + 0) ^ sw) * 8] = *(const uint4*)(gqh + o0);
    *(uint4*)&Qh[lr][((kb0 + 1) ^ sw) * 8] = *(const uint4*)(gqh + o0 + 8);
    *(uint4*)&Ql[lr][((kb0 + 0) ^ sw) * 8] = *(const uint4*)(gql + o0);
    *(uint4*)&Ql[lr][((kb0 + 1) ^ sw) * 8] = *(const uint4*)(gql + o0 + 8);
  }
  f32x4 o_[4] = {};
  float m_r[4] = {-INFINITY, -INFINITY, -INFINITY, -INFINITY};
  float l_r[4] = {0.0f, 0.0f, 0.0f, 0.0f};
  float alpha[4];
  for (int kt = 0; kt < 16; kt++) {
    __syncthreads();          // prev PV reads of KP(P)/VT done
    { // stage K rows + VT rows (pure coalesced copies, V pre-transposed)
      const size_t ko = hb + (size_t)(kt * 64 + lr) * 64 + lc;
      *(uint4*)&KP[0][lr][lc]     = *(const uint4*)(gkh + ko);
      *(uint4*)&KP[0][lr][lc + 8] = *(const uint4*)(gkh + ko + 8);
      *(uint4*)&KP[1][lr][lc]     = *(const uint4*)(gkl + ko);
      *(uint4*)&KP[1][lr][lc + 8] = *(const uint4*)(gkl + ko + 8);
      const size_t vo = hb + (size_t)lr * 1024 + kt * 64 + lc;
      *(uint4*)&VTh[lr][lc]     = *(const uint4*)(gvh + vo);
      *(uint4*)&VTh[lr][lc + 8] = *(const uint4*)(gvh + vo + 8);
      *(uint4*)&VTl[lr][lc]     = *(const uint4*)(gvl + vo);
      *(uint4*)&VTl[lr][lc + 8] = *(const uint4*)(gvl + vo + 8);
    }
    __syncthreads();          // staging visible
    // QK^T: S[q][k] = Q . K (both row-frags -> D = A*B^T), bf16x3
    f32x4 sacc[4] = {};
#pragma unroll
    for (int ks = 0; ks < 2; ks++) {
      const int kb = ks * 4 + fg;
      const short8v qh_ = *(const short8v*)&Qh[wv * 16 + fr][(kb ^ (fr & 7)) * 8];
      const short8v ql_ = *(const short8v*)&Ql[wv * 16 + fr][(kb ^ (fr & 7)) * 8];
#pragma unroll
      for (int nn = 0; nn < 4; nn++) {
        const short8v kh_ = *(const short8v*)&KP[0][nn * 16 + fr][ks * 32 + fg * 8];
        const short8v kl_ = *(const short8v*)&KP[1][nn * 16 + fr][ks * 32 + fg * 8];
        sacc[nn] = __builtin_amdgcn_mfma_f32_16x16x32_bf16(ql_, kh_, sacc[nn], 0, 0, 0);
        sacc[nn] = __builtin_amdgcn_mfma_f32_16x16x32_bf16(qh_, kl_, sacc[nn], 0, 0, 0);
        sacc[nn] = __builtin_amdgcn_mfma_f32_16x16x32_bf16(qh_, kh_, sacc[nn], 0, 0, 0);
      }
    }
    // online softmax (rows = fg*4 + r, cols spread over 16 lanes x 4 nn)
#pragma unroll
    for (int r = 0; r < 4; r++) {
      float tmax = fmaxf(fmaxf(sacc[0][r], sacc[1][r]), fmaxf(sacc[2][r], sacc[3][r]));
#pragma unroll
      for (int off = 8; off; off >>= 1) tmax = fmaxf(tmax, __shfl_xor(tmax, off, 16));
      const float mn = fmaxf(m_r[r], tmax);
      alpha[r] = expf(m_r[r] - mn);
      float s_ = 0.0f;
#pragma unroll
      for (int nn = 0; nn < 4; nn++) { sacc[nn][r] = expf(sacc[nn][r] - mn); s_ += sacc[nn][r]; }
#pragma unroll
      for (int off = 8; off; off >>= 1) s_ += __shfl_xor(s_, off, 16);
      m_r[r] = mn;
      l_r[r] = l_r[r] * alpha[r] + s_;
    }
    __syncthreads();          // all K-frag reads done -> overwrite region as P
#pragma unroll
    for (int nn = 0; nn < 4; nn++)
#pragma unroll
      for (int r = 0; r < 4; r++)
        Pf[(wv * 16 + fg * 4 + r) * 68 + nn * 16 + fr] = sacc[nn][r];
    __syncthreads();          // P visible (cross-lane)
#pragma unroll
    for (int nd = 0; nd < 4; nd++)
#pragma unroll
      for (int r = 0; r < 4; r++) o_[nd][r] *= alpha[r];
    // PV: O[q][d] = P . V = A(P rows) * B(VT rows)^T, bf16x3
#pragma unroll
    for (int ks = 0; ks < 2; ks++) {
      float pf[8];
      *(float4*)&pf[0] = *(const float4*)&Pf[(wv * 16 + fr) * 68 + ks * 32 + fg * 8];
      *(float4*)&pf[4] = *(const float4*)&Pf[(wv * 16 + fr) * 68 + ks * 32 + fg * 8 + 4];
      short8v ph_, pl_;
      split8(pf, ph_, pl_);
#pragma unroll
      for (int nd = 0; nd < 4; nd++) {
        const short8v vh_ = *(const short8v*)&VTh[nd * 16 + fr][ks * 32 + fg * 8];
        const short8v vl_ = *(const short8v*)&VTl[nd * 16 + fr][ks * 32 + fg * 8];
        o_[nd] = __builtin_amdgcn_mfma_f32_16x16x32_bf16(pl_, vh_, o_[nd], 0, 0, 0);
        o_[nd] = __builtin_amdgcn_mfma_f32_16x16x32_bf16(ph_, vl_, o_[nd], 0, 0, 0);
        o_[nd] = __builtin_amdgcn_mfma_f32_16x16x32_bf16(ph_, vh_, o_[nd], 0, 0, 0);
      }
    }
  }
  // epilogue: bf16 hi/lo om for MFMA proj. col = fr (d in 16-block), row = fg*4+r.
#pragma unroll
  for (int r = 0; r < 4; r++) {
    const float inv = 1.0f / l_r[r];
    const int t = qb * 64 + wv * 16 + fg * 4 + r;
    const size_t ob = (size_t)(bz * ND_ + t) * C_ + h * 64;
#pragma unroll
    for (int nd = 0; nd < 4; nd++) {
      const float f = o_[nd][r] * inv;
      const unsigned short hv = f2bf_rtne(f);
      const float fh = __uint_as_float((unsigned)hv << 16);
      const unsigned short lv = f2bf_rtne(f - fh);
      omh[ob + nd * 16 + fr] = hv;
      oml[ob + nd * 16 + fr] = lv;
    }
  }
}

// ---------------------------------------------------------------------------
// K12: proj GEMM via bf16x3 MFMA. M=4096, N=1024, K=1024. ym = om@Wp^T + bp
// ---------------------------------------------------------------------------
__global__ __launch_bounds__(256) void k_proj_mfma(
    const unsigned short* __restrict__ omh, const unsigned short* __restrict__ oml,
    const unsigned short* __restrict__ wph, const unsigned short* __restrict__ wpl,
    const float* __restrict__ bp, float* __restrict__ ym) {
  __shared__ __align__(16) unsigned short Ahs[128][40], Als[128][40];
  __shared__ __align__(16) unsigned short Bhs[128][40], Bls[128][40];
  const int nb = blockIdx.x;   // 8
  const int mb = blockIdx.y;   // 32
  const int tid = threadIdx.x;
  const int lane = tid & 63, wv = tid >> 6;
  const int wr = wv >> 1, wc = wv & 1;
  const int fr = lane & 15, fg = lane >> 4;
  const int srow = tid >> 1, scol = (tid & 1) * 16;
  const size_t abase = (size_t)(mb * 128 + srow) * C_ + scol;
  const size_t bbase = (size_t)(nb * 128 + srow) * C_ + scol;
  f32x4 acc[4][4] = {};
  for (int k0 = 0; k0 < C_; k0 += 32) {
    __syncthreads();
    *(uint4*)&Ahs[srow][scol]     = *(const uint4*)(omh + abase + k0);
    *(uint4*)&Ahs[srow][scol + 8] = *(const uint4*)(omh + abase + k0 + 8);
    *(uint4*)&Als[srow][scol]     = *(const uint4*)(oml + abase + k0);
    *(uint4*)&Als[srow][scol + 8] = *(const uint4*)(oml + abase + k0 + 8);
    *(uint4*)&Bhs[srow][scol]     = *(const uint4*)(wph + bbase + k0);
    *(uint4*)&Bhs[srow][scol + 8] = *(const uint4*)(wph + bbase + k0 + 8);
    *(uint4*)&Bls[srow][scol]     = *(const uint4*)(wpl + bbase + k0);
    *(uint4*)&Bls[srow][scol + 8] = *(const uint4*)(wpl + bbase + k0 + 8);
    __syncthreads();
    short8v bh[4], bl[4];
#pragma unroll
    for (int j = 0; j < 4; j++) {
      bh[j] = *(const short8v*)&Bhs[wc * 64 + j * 16 + fr][fg * 8];
      bl[j] = *(const short8v*)&Bls[wc * 64 + j * 16 + fr][fg * 8];
    }
#pragma unroll
    for (int i = 0; i < 4; i++) {
      const short8v ah = *(const short8v*)&Ahs[wr * 64 + i * 16 + fr][fg * 8];
      const short8v al = *(const short8v*)&Als[wr * 64 + i * 16 + fr][fg * 8];
#pragma unroll
      for (int j = 0; j < 4; j++) {
        acc[i][j] = __builtin_amdgcn_mfma_f32_16x16x32_bf16(al, bh[j], acc[i][j], 0, 0, 0);
        acc[i][j] = __builtin_amdgcn_mfma_f32_16x16x32_bf16(ah, bl[j], acc[i][j], 0, 0, 0);
        acc[i][j] = __builtin_amdgcn_mfma_f32_16x16x32_bf16(ah, bh[j], acc[i][j], 0, 0, 0);
      }
    }
  }
#pragma unroll
  for (int j = 0; j < 4; j++) {
    const int n = nb * 128 + wc * 64 + j * 16 + fr;
    const float bias = bp[n];
#pragma unroll
    for (int i = 0; i < 4; i++)
#pragma unroll
      for (int r = 0; r < 4; r++) {
        const int m = mb * 128 + wr * 64 + i * 16 + fg * 4 + r;
        ym[(size_t)m * C_ + n] = acc[i][j][r] + bias;
      }
  }
}

// K13: scatter merged rows back to all 4096 tokens
__global__ __launch_bounds__(256) void k_unmerge(const float* __restrict__ ym,
                                                 const int* __restrict__ rowmap,
                                                 float* __restrict__ out) {
  const int blk = blockIdx.x;                 // B_*N_
  const int bz = blk >> 12;
  const int r = rowmap[blk];
  const float4* src = (const float4*)(ym + ((size_t)bz * ND_ + r) * C_);
  float4* dst = (float4*)(out + (size_t)blk * C_);
  dst[threadIdx.x] = src[threadIdx.x];
}

// ---------------------------------------------------------------------------
extern "C" void kernel_launch(void* const* d_in, const int* in_sizes, int n_in,
                              void* d_out, int out_size, void* d_ws, size_t ws_size,
                              hipStream_t stream) {
  const float* x    = (const float*)d_in[0];
  const float* Wqkv = (const float*)d_in[1];
  const float* Wp   = (const float*)d_in[2];
  const float* bp   = (const float*)d_in[3];
  char* ws = (char*)d_ws;
  double* dinv    = (double*)(ws + 0);          //  131072 B
  int*   b_idx    = (int*)(ws + 131072);
  int*   a_idx    = (int*)(ws + 135168);
  int*   node_idx = (int*)(ws + 147456);
  int*   cnt      = (int*)(ws + 196608);
  int*   rowmap   = (int*)(ws + 212992);
  int*   flagr    = (int*)(ws + 278528);
  float* pv1      = (float*)(ws + 327680);
  int*   pi1      = (int*)(ws + 1114112);
  float* pv2      = (float*)(ws + 1900544);
  int*   pi2      = (int*)(ws + 2686976);
  // Lifetime-disjoint aliased regions (all hand-checked, stream-ordered):
  // [3,473,408 .. 70,582,272): xh/xl (prep->scores)
  unsigned short* xh = (unsigned short*)(ws + 3473408);    // 33,554,432 B
  unsigned short* xl = (unsigned short*)(ws + 37027840);   // 33,554,432 B
  // xm fp32 (merge_init->merge_scale) aliases xh head
  float* xm = (float*)(ws + 3473408);                      // 16,777,216 B
  // xmh/xml (merge_scale->qkv) alias xh tail
  unsigned short* xmh = (unsigned short*)(ws + 20250624);  // 8,388,608 B
  unsigned short* xml = (unsigned short*)(ws + 28639232);  // 8,388,608 B
  // Wq hi/lo (prep_w->qkv) alias xl head
  unsigned short* wqh = (unsigned short*)(ws + 37027840);  // 6,291,456 B
  unsigned short* wql = (unsigned short*)(ws + 43319296);  // 6,291,456 B
  // Q/K/V hi-lo (qkv->attn): Q aliases dead xm; K/V in fresh region
  unsigned short* gqh = (unsigned short*)(ws + 3473408);   // 8,388,608 B
  unsigned short* gql = (unsigned short*)(ws + 11862016);  // 8,388,608 B
  unsigned short* gkh = (unsigned short*)(ws + 49610752);  // 8,388,608 B
  unsigned short* gkl = (unsigned short*)(ws + 57999360);  // 8,388,608 B
  unsigned short* gvh = (unsigned short*)(ws + 66387968);  // 8,388,608 B
  unsigned short* gvl = (unsigned short*)(ws + 74776576);  // 8,388,608 B  (ends 83,165,184)
  // Wp hi/lo (prep_w->proj), tail region
  unsigned short* wph = (unsigned short*)(ws + 83165184);  // 2,097,152 B
  unsigned short* wpl = (unsigned short*)(ws + 85262336);  // 2,097,152 B  (ends 87,359,488)
  // om hi/lo (attn->proj) alias dead xmh/xml
  unsigned short* omh = (unsigned short*)(ws + 20250624);  // 8,388,608 B
  unsigned short* oml = (unsigned short*)(ws + 28639232);  // 8,388,608 B
  // ym fp32 (proj->unmerge) aliases dead gqh/gql
  float* ym = (float*)(ws + 3473408);                      // 16,777,216 B
  float* out = (float*)d_out;

  hipMemsetAsync(cnt, 0, B_ * ND_ * sizeof(int), stream);
  k_init_indices<<<1, 1024, 0, stream>>>(b_idx, a_idx);
  k_row_norms<<<B_ * N_, 256, 0, stream>>>(x, dinv);
  k_prep<<<B_ * N_, 256, 0, stream>>>(x, dinv, xh, xl);
  k_scores_mfma<<<dim3(16, 48, B_), 256, 0, stream>>>(xh, xl, a_idx, b_idx, pv1, pi1, pv2, pi2);
  k_prep_w<<<4096, 256, 0, stream>>>(Wqkv, Wp, wqh, wql, wph, wpl);  // after scores (xl dead)
  k_finalize<<<(B_ * NA_) / 256, 256, 0, stream>>>(pv1, pi1, pv2, pi2, node_idx, flagr);
  k_recheck<<<B_ * NA_, 256, 0, stream>>>(x, dinv, a_idx, b_idx, pv1, pi1, pv2, pi2, flagr, node_idx);
  k_counts_rowmap<<<(B_ * N_) / 256, 256, 0, stream>>>(a_idx, b_idx, node_idx, cnt, rowmap);
  k_merge_init<<<B_ * ND_, 256, 0, stream>>>(x, b_idx, xm);
  k_merge_add<<<B_ * NA_, 256, 0, stream>>>(x, a_idx, node_idx, xm);
  k_merge_scale<<<B_ * ND_, 256, 0, stream>>>(xm, cnt, xmh, xml);
  k_qkv_mfma<<<dim3(24, 32), 256, 0, stream>>>(xmh, xml, wqh, wql,
                                               gqh, gql, gkh, gkl, gvh, gvl);
  k_attn<<<dim3(16, 16, B_), 256, 0, stream>>>(gqh, gql, gkh, gkl, gvh, gvl, omh, oml);
  k_proj_mfma<<<dim3(8, 32), 256, 0, stream>>>(omh, oml, wph, wpl, bp, ym);
  k_unmerge<<<B_ * N_, 256, 0, stream>>>(ym, rowmap, out);
}